// Round 1
// baseline (452.632 us; speedup 1.0000x reference)
//
#include <hip/hip_runtime.h>
#include <cstdint>
#include <cstddef>

#define NNODES 8192
#define NEDGES 262144

__device__ __forceinline__ float leaky(float v){ return v > 0.f ? v : 0.01f*v; }

__device__ __forceinline__ unsigned fmap(float f){
  unsigned u = __float_as_uint(f);
  return (u & 0x80000000u) ? ~u : (u | 0x80000000u);
}
__device__ __forceinline__ float funmap(unsigned u){
  return (u & 0x80000000u) ? __uint_as_float(u & 0x7FFFFFFFu) : __uint_as_float(~u);
}

// ---------------- init: zero degree arrays, colsum accum, pool accum ----------------
__global__ void k_init(int* degc, int* degr, float* Sall, unsigned* poolu, int n){
  int t = blockIdx.x*blockDim.x + threadIdx.x;
  if (t < n){ degc[t]=0; degr[t]=0; }
  if (t < 256) Sall[t]=0.f;
  if (t < 64) poolu[t]=0u;
}

// ---------------- degrees (col = destination for GCN; row = destination for attention) ----
__global__ void k_degree(const int* __restrict__ ei, int* degc, int* degr, int E){
  int e = blockIdx.x*blockDim.x + threadIdx.x;
  if (e >= E) return;
  atomicAdd(&degc[ei[E+e]], 1);
  atomicAdd(&degr[ei[e]],   1);
}

// ---------------- single-block exclusive scan over n=8192 (1024 thr x 8) ----------------
__global__ __launch_bounds__(1024) void k_scan(const int* __restrict__ deg, int* __restrict__ ptr, int n){
  __shared__ int part[1024];
  int t = threadIdx.x;
  const int per = 8;                 // n/1024
  int base = t*per;
  int loc[8]; int s = 0;
  #pragma unroll
  for (int q=0;q<per;q++){ loc[q]=s; s += deg[base+q]; }
  part[t]=s; __syncthreads();
  for (int o=1;o<1024;o<<=1){
    int v = (t>=o)? part[t-o] : 0;
    __syncthreads();
    if (t>=o) part[t]+=v;
    __syncthreads();
  }
  int prev = t ? part[t-1] : 0;
  #pragma unroll
  for (int q=0;q<per;q++) ptr[base+q] = prev + loc[q];
  if (t==1023) ptr[n] = part[1023];
}

// ---------------- dinv (from col-degree + self loop), cursors ----------------
__global__ void k_prep(const int* __restrict__ degc, const int* __restrict__ ptrc,
                       const int* __restrict__ ptrr,
                       float* dinv, int* curc, int* curr, int n){
  int i = blockIdx.x*blockDim.x + threadIdx.x;
  if (i>=n) return;
  dinv[i] = rsqrtf((float)(degc[i]+1));
  curc[i] = ptrc[i];
  curr[i] = ptrr[i];
}

// ---------------- scatter into two CSRs ----------------
__global__ void k_scatter(const int* __restrict__ ei, int* curc, int* curr,
                          int* csrc, int* csri, int* csrd, int E){
  int e = blockIdx.x*blockDim.x + threadIdx.x;
  if (e>=E) return;
  int r = ei[e], c = ei[E+e];
  int p1 = atomicAdd(&curc[c],1); csrc[p1] = r;                 // grouped by destination col
  int p2 = atomicAdd(&curr[r],1); csrd[p2] = c; csri[p2] = r;   // grouped by row (attention dst)
}

// ---------------- fp32 tiled GEMM: C[M,N] = A[M,K] @ W[K,N] (+bias) ----------------
// 64x64 tile, BK=16, 256 threads, 4x4 per thread
__global__ __launch_bounds__(256) void gemm_bias(const float* __restrict__ A,
    const float* __restrict__ W, const float* __restrict__ bias,
    float* __restrict__ C, int M, int K, int N){
  __shared__ float As[16][68];
  __shared__ float Ws[16][64];
  int t  = threadIdx.x;
  int m0 = blockIdx.x * 64;
  int n0 = blockIdx.y * 64;
  int tr = t >> 4, tc = t & 15;
  int ar = t >> 2;            // 0..63 row in tile
  int ak = (t & 3) * 4;       // k offset
  int wk = t >> 4;            // 0..15
  int wn = (t & 15) * 4;      // col offset
  float acc[4][4] = {};
  for (int k0 = 0; k0 < K; k0 += 16){
    float4 av = *(const float4*)(A + (size_t)(m0 + ar) * K + k0 + ak);
    float4 wv = *(const float4*)(W + (size_t)(k0 + wk) * N + n0 + wn);
    As[ak+0][ar] = av.x; As[ak+1][ar] = av.y; As[ak+2][ar] = av.z; As[ak+3][ar] = av.w;
    *(float4*)&Ws[wk][wn] = wv;
    __syncthreads();
    #pragma unroll
    for (int kk = 0; kk < 16; ++kk){
      float a[4], w[4];
      *(float4*)a = *(const float4*)&As[kk][tr*4];
      *(float4*)w = *(const float4*)&Ws[kk][tc*4];
      #pragma unroll
      for (int i=0;i<4;i++)
        #pragma unroll
        for (int j=0;j<4;j++)
          acc[i][j] = fmaf(a[i], w[j], acc[i][j]);
    }
    __syncthreads();
  }
  float4 bv = make_float4(0.f,0.f,0.f,0.f);
  if (bias) bv = *(const float4*)(bias + n0 + tc*4);
  #pragma unroll
  for (int i=0;i<4;i++){
    float4 v;
    v.x = acc[i][0]+bv.x; v.y = acc[i][1]+bv.y; v.z = acc[i][2]+bv.z; v.w = acc[i][3]+bv.w;
    *(float4*)(C + (size_t)(m0 + tr*4 + i)*N + n0 + tc*4) = v;
  }
}

// ---------------- GCN aggregation: out[c,f] = leaky( b[f] + dinv[c]^2*xw[c,f]
//                  + sum_{r in in(c)} dinv[r]*dinv[c]*xw[r,f] ) ; blockDim.x == F ----
__global__ void k_agg(const float* __restrict__ xw, const float* __restrict__ b,
                      const int* __restrict__ ptr, const int* __restrict__ src,
                      const float* __restrict__ dinv, float* __restrict__ outp, int F){
  int c = blockIdx.x, f = threadIdx.x;
  float dc = dinv[c];
  float acc = dc*dc*xw[(size_t)c*F + f];
  int e0 = ptr[c], e1 = ptr[c+1];
  for (int e=e0; e<e1; ++e){
    int r = src[e];
    acc = fmaf(dinv[r]*dc, xw[(size_t)r*F + f], acc);
  }
  outp[(size_t)c*F + f] = leaky(acc + b[f]);
}

// ---------------- column sums of h2 [n,256] -> Sall[256] ----------------
__global__ void k_colsum(const float* __restrict__ h2, float* Sall, int n){
  int f = threadIdx.x;
  float acc = 0.f;
  int r0 = blockIdx.x * 128;
  for (int r = r0; r < r0 + 128; ++r) acc += h2[(size_t)r*256 + f];
  atomicAdd(&Sall[f], acc);
}

// ---------------- per-edge scores: es[e] = exp(q_row . k_col), one wave per edge ----
__global__ __launch_bounds__(256) void k_scores(const float* __restrict__ quer,
    const float* __restrict__ keys, const int* __restrict__ csri,
    const int* __restrict__ csrd, float* __restrict__ es, int E){
  int w = threadIdx.x >> 6, lane = threadIdx.x & 63;
  int e = blockIdx.x*4 + w;
  if (e >= E) return;
  int i = csri[e], j = csrd[e];
  float4 a = *(const float4*)(quer + (size_t)i*256 + lane*4);
  float4 b = *(const float4*)(keys + (size_t)j*256 + lane*4);
  float s = a.x*b.x + a.y*b.y + a.z*b.z + a.w*b.w;
  #pragma unroll
  for (int m=32; m; m>>=1) s += __shfl_xor(s, m, 64);
  if (lane==0) es[e] = __expf(s);
}

// ---------------- attention aggregate: hatt[i,f] = (Sall[f] + sum (es-1)h2[j,f]) / den_i ----
__global__ __launch_bounds__(256) void k_attn(const float* __restrict__ h2,
    const float* __restrict__ Sall, const int* __restrict__ ptrr,
    const int* __restrict__ csrd, const float* __restrict__ es,
    float* __restrict__ hatt, int n){
  int i = blockIdx.x, f = threadIdx.x;
  float acc = Sall[f];
  float dacc = 0.f;
  int e0 = ptrr[i], e1 = ptrr[i+1];
  for (int e=e0; e<e1; ++e){
    int j = csrd[e];
    float w = es[e];
    dacc += w;
    acc = fmaf(w - 1.0f, h2[(size_t)j*256 + f], acc);
  }
  float den = (float)(n - (e1 - e0)) + dacc;
  hatt[(size_t)i*256 + f] = acc / den;
}

// ---------------- fused: conv3 aggregation + bias + leaky + residual + LayerNorm ----
__global__ __launch_bounds__(64) void k_z(const float* __restrict__ hw3,
    const float* __restrict__ b3, const int* __restrict__ ptrc,
    const int* __restrict__ csrc, const float* __restrict__ dinv,
    const float* __restrict__ resid, const float* __restrict__ lng,
    const float* __restrict__ lnb, float* __restrict__ z){
  int c = blockIdx.x, f = threadIdx.x;
  float dc = dinv[c];
  float acc = dc*dc*hw3[(size_t)c*64 + f];
  int e0 = ptrc[c], e1 = ptrc[c+1];
  for (int e=e0; e<e1; ++e){
    int r = csrc[e];
    acc = fmaf(dinv[r]*dc, hw3[(size_t)r*64 + f], acc);
  }
  float v = leaky(acc + b3[f]) + resid[(size_t)c*64 + f];
  float s = v;
  #pragma unroll
  for (int m=32; m; m>>=1) s += __shfl_xor(s, m, 64);
  float mu = s * (1.0f/64.0f);
  float d = v - mu;
  float s2 = d*d;
  #pragma unroll
  for (int m=32; m; m>>=1) s2 += __shfl_xor(s2, m, 64);
  float var = s2 * (1.0f/64.0f);
  z[(size_t)c*64 + f] = d * rsqrtf(var + 1e-5f) * lng[f] + lnb[f];
}

// ---------------- max pool over nodes -> pooled_u[64] (monotonic uint atomicMax) ----
__global__ __launch_bounds__(256) void k_pool(const float* __restrict__ z,
    unsigned* __restrict__ poolu, int n){
  int f = threadIdx.x & 63, rg = threadIdx.x >> 6;
  float m = -3.402823466e38f;
  int r0 = blockIdx.x * 128;
  for (int r = r0 + rg; r < r0 + 128; r += 4) m = fmaxf(m, z[(size_t)r*64 + f]);
  __shared__ float sh[4][64];
  sh[rg][f] = m; __syncthreads();
  if (rg == 0){
    m = fmaxf(fmaxf(sh[0][f],sh[1][f]), fmaxf(sh[2][f],sh[3][f]));
    atomicMax(&poolu[f], fmap(m));
  }
}

// ---------------- final: out[16] = pooled @ Wf + bf ----------------
__global__ __launch_bounds__(64) void k_final(const unsigned* __restrict__ poolu,
    const float* __restrict__ Wf, const float* __restrict__ bfv, float* __restrict__ out){
  __shared__ float p[64];
  int t = threadIdx.x;
  p[t] = funmap(poolu[t]);
  __syncthreads();
  if (t < 16){
    float acc = bfv[t];
    #pragma unroll
    for (int f=0; f<64; ++f) acc = fmaf(p[f], Wf[f*16 + t], acc);
    out[t] = acc;
  }
}

extern "C" void kernel_launch(void* const* d_in, const int* in_sizes, int n_in,
                              void* d_out, int out_size, void* d_ws, size_t ws_size,
                              hipStream_t stream){
  const float* x   = (const float*)d_in[0];
  const int*   ei  = (const int*)d_in[1];
  const float* W1  = (const float*)d_in[2];
  const float* b1  = (const float*)d_in[3];
  const float* W2  = (const float*)d_in[4];
  const float* b2  = (const float*)d_in[5];
  const float* W3  = (const float*)d_in[6];
  const float* b3  = (const float*)d_in[7];
  const float* Wk  = (const float*)d_in[8];
  const float* bk  = (const float*)d_in[9];
  const float* Wq  = (const float*)d_in[10];
  const float* bq  = (const float*)d_in[11];
  const float* Wr  = (const float*)d_in[12];
  const float* br  = (const float*)d_in[13];
  const float* lng = (const float*)d_in[14];
  const float* lnb = (const float*)d_in[15];
  const float* Wf  = (const float*)d_in[16];
  const float* bfv = (const float*)d_in[17];
  float* out = (float*)d_out;

  const int n = NNODES, E = NEDGES;
  char* ws = (char*)d_ws; size_t off = 0;
  auto alloc = [&](size_t bytes)->void*{
    void* p = ws + off; off += (bytes + 255) & ~(size_t)255; return p;
  };
  float* xw1  = (float*)alloc((size_t)n*128*4);
  float* h1   = (float*)alloc((size_t)n*128*4);
  float* h1w2 = (float*)alloc((size_t)n*256*4);
  float* h2   = (float*)alloc((size_t)n*256*4);
  float* keys = (float*)alloc((size_t)n*256*4);
  float* quer = (float*)alloc((size_t)n*256*4);
  float* hatt = (float*)alloc((size_t)n*256*4);
  float* hw3  = (float*)alloc((size_t)n*64*4);
  float* resid= (float*)alloc((size_t)n*64*4);
  float* zbuf = (float*)alloc((size_t)n*64*4);
  float* es   = (float*)alloc((size_t)E*4);
  float* dinv = (float*)alloc((size_t)n*4);
  float* Sall = (float*)alloc(256*4);
  int* degc = (int*)alloc((size_t)n*4);
  int* degr = (int*)alloc((size_t)n*4);
  int* ptrc = (int*)alloc((size_t)(n+1)*4);
  int* ptrr = (int*)alloc((size_t)(n+1)*4);
  int* curc = (int*)alloc((size_t)n*4);
  int* curr = (int*)alloc((size_t)n*4);
  int* csrc = (int*)alloc((size_t)E*4);
  int* csri = (int*)alloc((size_t)E*4);
  int* csrd = (int*)alloc((size_t)E*4);
  unsigned* poolu = (unsigned*)alloc(64*4);

  // graph structure
  k_init   <<<dim3((n+255)/256), 256, 0, stream>>>(degc, degr, Sall, poolu, n);
  k_degree <<<dim3(E/256),       256, 0, stream>>>(ei, degc, degr, E);
  k_scan   <<<1, 1024, 0, stream>>>(degc, ptrc, n);
  k_scan   <<<1, 1024, 0, stream>>>(degr, ptrr, n);
  k_prep   <<<dim3((n+255)/256), 256, 0, stream>>>(degc, ptrc, ptrr, dinv, curc, curr, n);
  k_scatter<<<dim3(E/256),       256, 0, stream>>>(ei, curc, curr, csrc, csri, csrd, E);

  auto gemm = [&](const float* A, const float* W, const float* bias, float* C,
                  int M, int K, int N){
    gemm_bias<<<dim3(M/64, N/64), 256, 0, stream>>>(A, W, bias, C, M, K, N);
  };

  gemm(x, Wr, br, resid, n, 128, 64);          // residual = x@Wr + br
  gemm(x, W1, nullptr, xw1, n, 128, 128);      // conv1 transform
  k_agg<<<n, 128, 0, stream>>>(xw1, b1, ptrc, csrc, dinv, h1, 128);
  gemm(h1, W2, nullptr, h1w2, n, 128, 256);    // conv2 transform
  k_agg<<<n, 256, 0, stream>>>(h1w2, b2, ptrc, csrc, dinv, h2, 256);
  gemm(h2, Wk, bk, keys, n, 256, 256);
  gemm(h2, Wq, bq, quer, n, 256, 256);
  k_colsum<<<64, 256, 0, stream>>>(h2, Sall, n);
  k_scores<<<dim3(E/4), 256, 0, stream>>>(quer, keys, csri, csrd, es, E);
  k_attn  <<<n, 256, 0, stream>>>(h2, Sall, ptrr, csrd, es, hatt, n);
  gemm(hatt, W3, nullptr, hw3, n, 256, 64);    // conv3 transform
  k_z     <<<n, 64, 0, stream>>>(hw3, b3, ptrc, csrc, dinv, resid, lng, lnb, zbuf);
  k_pool  <<<64, 256, 0, stream>>>(zbuf, poolu, n);
  k_final <<<1, 64, 0, stream>>>(poolu, Wf, bfv, out);
}

// Round 2
// 409.073 us; speedup vs baseline: 1.1065x; 1.1065x over previous
//
#include <hip/hip_runtime.h>
#include <hip/hip_fp16.h>
#include <cstdint>
#include <cstddef>

#define NNODES 8192
#define NEDGES 262144

__device__ __forceinline__ float leaky(float v){ return v > 0.f ? v : 0.01f*v; }

__device__ __forceinline__ unsigned fmap(float f){
  unsigned u = __float_as_uint(f);
  return (u & 0x80000000u) ? ~u : (u | 0x80000000u);
}
__device__ __forceinline__ float funmap(unsigned u){
  return (u & 0x80000000u) ? __uint_as_float(u & 0x7FFFFFFFu) : __uint_as_float(~u);
}

// ---------------- init: zero degree arrays, colsum accum, pool accum ----------------
__global__ void k_init(int* degc, int* degr, float* Sall, unsigned* poolu, int n){
  int t = blockIdx.x*blockDim.x + threadIdx.x;
  if (t < n){ degc[t]=0; degr[t]=0; }
  if (t < 256) Sall[t]=0.f;
  if (t < 64) poolu[t]=0u;
}

// ---------------- fp32 -> fp16 copy ----------------
__global__ void k_half(const float* __restrict__ a, __half* __restrict__ b, int n){
  int t = blockIdx.x*blockDim.x + threadIdx.x;
  if (t < n) b[t] = __float2half(a[t]);
}

// ---------------- degrees (col = GCN dst; row = attention dst) ----------------
__global__ void k_degree(const int* __restrict__ ei, int* degc, int* degr, int E){
  int e = blockIdx.x*blockDim.x + threadIdx.x;
  if (e >= E) return;
  atomicAdd(&degc[ei[E+e]], 1);
  atomicAdd(&degr[ei[e]],   1);
}

// ---------------- single-block exclusive scan over n=8192 ----------------
__global__ __launch_bounds__(1024) void k_scan(const int* __restrict__ deg, int* __restrict__ ptr, int n){
  __shared__ int part[1024];
  int t = threadIdx.x;
  const int per = 8;
  int base = t*per;
  int loc[8]; int s = 0;
  #pragma unroll
  for (int q=0;q<per;q++){ loc[q]=s; s += deg[base+q]; }
  part[t]=s; __syncthreads();
  for (int o=1;o<1024;o<<=1){
    int v = (t>=o)? part[t-o] : 0;
    __syncthreads();
    if (t>=o) part[t]+=v;
    __syncthreads();
  }
  int prev = t ? part[t-1] : 0;
  #pragma unroll
  for (int q=0;q<per;q++) ptr[base+q] = prev + loc[q];
  if (t==1023) ptr[n] = part[1023];
}

// ---------------- dinv + cursors ----------------
__global__ void k_prep(const int* __restrict__ degc, const int* __restrict__ ptrc,
                       const int* __restrict__ ptrr,
                       float* dinv, int* curc, int* curr, int n){
  int i = blockIdx.x*blockDim.x + threadIdx.x;
  if (i>=n) return;
  dinv[i] = rsqrtf((float)(degc[i]+1));
  curc[i] = ptrc[i];
  curr[i] = ptrr[i];
}

// ---------------- scatter into two CSRs ----------------
__global__ void k_scatter(const int* __restrict__ ei, int* curc, int* curr,
                          int* csrc, int* csri, int* csrd, int E){
  int e = blockIdx.x*blockDim.x + threadIdx.x;
  if (e>=E) return;
  int r = ei[e], c = ei[E+e];
  int p1 = atomicAdd(&curc[c],1); csrc[p1] = r;
  int p2 = atomicAdd(&curr[r],1); csrd[p2] = c; csri[p2] = r;
}

// ---------------- fp32 tiled GEMM: C = A[M,K] @ W[K,N] (+bias, +opt leaky)
//                  dual-store: Cf (fp32, nullable) and Ch (fp16, nullable) ----
__global__ __launch_bounds__(256) void gemm_bias(const float* __restrict__ A,
    const float* __restrict__ W, const float* __restrict__ bias,
    float* __restrict__ Cf, __half* __restrict__ Ch,
    int M, int K, int N, int act){
  __shared__ float As[16][68];
  __shared__ float Ws[16][64];
  int t  = threadIdx.x;
  int m0 = blockIdx.x * 64;
  int n0 = blockIdx.y * 64;
  int tr = t >> 4, tc = t & 15;
  int ar = t >> 2;
  int ak = (t & 3) * 4;
  int wk = t >> 4;
  int wn = (t & 15) * 4;
  float acc[4][4] = {};
  for (int k0 = 0; k0 < K; k0 += 16){
    float4 av = *(const float4*)(A + (size_t)(m0 + ar) * K + k0 + ak);
    float4 wv = *(const float4*)(W + (size_t)(k0 + wk) * N + n0 + wn);
    As[ak+0][ar] = av.x; As[ak+1][ar] = av.y; As[ak+2][ar] = av.z; As[ak+3][ar] = av.w;
    *(float4*)&Ws[wk][wn] = wv;
    __syncthreads();
    #pragma unroll
    for (int kk = 0; kk < 16; ++kk){
      float a[4], w[4];
      *(float4*)a = *(const float4*)&As[kk][tr*4];
      *(float4*)w = *(const float4*)&Ws[kk][tc*4];
      #pragma unroll
      for (int i=0;i<4;i++)
        #pragma unroll
        for (int j=0;j<4;j++)
          acc[i][j] = fmaf(a[i], w[j], acc[i][j]);
    }
    __syncthreads();
  }
  float4 bv = make_float4(0.f,0.f,0.f,0.f);
  if (bias) bv = *(const float4*)(bias + n0 + tc*4);
  #pragma unroll
  for (int i=0;i<4;i++){
    float v0 = acc[i][0]+bv.x, v1 = acc[i][1]+bv.y, v2 = acc[i][2]+bv.z, v3 = acc[i][3]+bv.w;
    if (act){ v0 = leaky(v0); v1 = leaky(v1); v2 = leaky(v2); v3 = leaky(v3); }
    size_t base = (size_t)(m0 + tr*4 + i)*N + n0 + tc*4;
    if (Cf){
      float4 v; v.x=v0; v.y=v1; v.z=v2; v.w=v3;
      *(float4*)(Cf + base) = v;
    }
    if (Ch){
      __half2* hp = (__half2*)(Ch + base);
      hp[0] = __floats2half2_rn(v0, v1);
      hp[1] = __floats2half2_rn(v2, v3);
    }
  }
}

// ---------------- GCN aggregation (pure): out[c,f] = dinv_c^2*in[c,f]
//                  + sum_r dinv_r*dinv_c*in[r,f] ; fp16 in, fp32 out; blockDim==F ----
__global__ void k_aggh(const __half* __restrict__ in, const int* __restrict__ ptr,
                       const int* __restrict__ src, const float* __restrict__ dinv,
                       float* __restrict__ outp, int F){
  int c = blockIdx.x, f = threadIdx.x;
  float dc = dinv[c];
  float acc = dc*dc*__half2float(in[(size_t)c*F + f]);
  int e0 = ptr[c], e1 = ptr[c+1];
  for (int e=e0; e<e1; ++e){
    int r = src[e];
    acc = fmaf(dinv[r]*dc, __half2float(in[(size_t)r*F + f]), acc);
  }
  outp[(size_t)c*F + f] = acc;
}

// ---------------- column sums of h2 [n,256] -> Sall[256] ----------------
__global__ void k_colsum(const float* __restrict__ h2, float* Sall, int n){
  int f = threadIdx.x;
  float acc = 0.f;
  int r0 = blockIdx.x * 128;
  for (int r = r0; r < r0 + 128; ++r) acc += h2[(size_t)r*256 + f];
  atomicAdd(&Sall[f], acc);
}

// ---------------- per-edge scores: es[e] = exp(q_i . k_j), one wave per edge (fp16 q,k) ----
__global__ __launch_bounds__(256) void k_scores(const __half* __restrict__ quer,
    const __half* __restrict__ keys, const int* __restrict__ csri,
    const int* __restrict__ csrd, float* __restrict__ es, int E){
  int w = threadIdx.x >> 6, lane = threadIdx.x & 63;
  int e = blockIdx.x*4 + w;
  if (e >= E) return;
  int i = csri[e], j = csrd[e];
  const __half2* qp = (const __half2*)(quer + (size_t)i*256) + lane*2;
  const __half2* kp = (const __half2*)(keys + (size_t)j*256) + lane*2;
  float2 a0 = __half22float2(qp[0]), a1 = __half22float2(qp[1]);
  float2 b0 = __half22float2(kp[0]), b1 = __half22float2(kp[1]);
  float s = a0.x*b0.x + a0.y*b0.y + a1.x*b1.x + a1.y*b1.y;
  #pragma unroll
  for (int m=32; m; m>>=1) s += __shfl_xor(s, m, 64);
  if (lane==0) es[e] = __expf(s);
}

// ---------------- attention aggregate: hatt[i,f] = (Sall[f] + sum (es-1)h2[j,f]) / den_i ----
__global__ __launch_bounds__(256) void k_attn(const __half* __restrict__ h2h,
    const float* __restrict__ Sall, const int* __restrict__ ptrr,
    const int* __restrict__ csrd, const float* __restrict__ es,
    float* __restrict__ hatt, int n){
  int i = blockIdx.x, f = threadIdx.x;
  float acc = Sall[f];
  float dacc = 0.f;
  int e0 = ptrr[i], e1 = ptrr[i+1];
  for (int e=e0; e<e1; ++e){
    int j = csrd[e];
    float w = es[e];
    dacc += w;
    acc = fmaf(w - 1.0f, __half2float(h2h[(size_t)j*256 + f]), acc);
  }
  float den = (float)(n - (e1 - e0)) + dacc;
  hatt[(size_t)i*256 + f] = acc / den;
}

// ---------------- fused: conv3 agg + bias + leaky + residual + LayerNorm ----
__global__ __launch_bounds__(64) void k_z(const __half* __restrict__ hw3h,
    const float* __restrict__ b3, const int* __restrict__ ptrc,
    const int* __restrict__ csrc, const float* __restrict__ dinv,
    const float* __restrict__ resid, const float* __restrict__ lng,
    const float* __restrict__ lnb, float* __restrict__ z){
  int c = blockIdx.x, f = threadIdx.x;
  float dc = dinv[c];
  float acc = dc*dc*__half2float(hw3h[(size_t)c*64 + f]);
  int e0 = ptrc[c], e1 = ptrc[c+1];
  for (int e=e0; e<e1; ++e){
    int r = csrc[e];
    acc = fmaf(dinv[r]*dc, __half2float(hw3h[(size_t)r*64 + f]), acc);
  }
  float v = leaky(acc + b3[f]) + resid[(size_t)c*64 + f];
  float s = v;
  #pragma unroll
  for (int m=32; m; m>>=1) s += __shfl_xor(s, m, 64);
  float mu = s * (1.0f/64.0f);
  float d = v - mu;
  float s2 = d*d;
  #pragma unroll
  for (int m=32; m; m>>=1) s2 += __shfl_xor(s2, m, 64);
  float var = s2 * (1.0f/64.0f);
  z[(size_t)c*64 + f] = d * rsqrtf(var + 1e-5f) * lng[f] + lnb[f];
}

// ---------------- max pool over nodes (monotonic uint atomicMax) ----------------
__global__ __launch_bounds__(256) void k_pool(const float* __restrict__ z,
    unsigned* __restrict__ poolu, int n){
  int f = threadIdx.x & 63, rg = threadIdx.x >> 6;
  float m = -3.402823466e38f;
  int r0 = blockIdx.x * 128;
  for (int r = r0 + rg; r < r0 + 128; r += 4) m = fmaxf(m, z[(size_t)r*64 + f]);
  __shared__ float sh[4][64];
  sh[rg][f] = m; __syncthreads();
  if (rg == 0){
    m = fmaxf(fmaxf(sh[0][f],sh[1][f]), fmaxf(sh[2][f],sh[3][f]));
    atomicMax(&poolu[f], fmap(m));
  }
}

// ---------------- final: out[16] = pooled @ Wf + bf ----------------
__global__ __launch_bounds__(64) void k_final(const unsigned* __restrict__ poolu,
    const float* __restrict__ Wf, const float* __restrict__ bfv, float* __restrict__ out){
  __shared__ float p[64];
  int t = threadIdx.x;
  p[t] = funmap(poolu[t]);
  __syncthreads();
  if (t < 16){
    float acc = bfv[t];
    #pragma unroll
    for (int f=0; f<64; ++f) acc = fmaf(p[f], Wf[f*16 + t], acc);
    out[t] = acc;
  }
}

extern "C" void kernel_launch(void* const* d_in, const int* in_sizes, int n_in,
                              void* d_out, int out_size, void* d_ws, size_t ws_size,
                              hipStream_t stream){
  const float* x   = (const float*)d_in[0];
  const int*   ei  = (const int*)d_in[1];
  const float* W1  = (const float*)d_in[2];
  const float* b1  = (const float*)d_in[3];
  const float* W2  = (const float*)d_in[4];
  const float* b2  = (const float*)d_in[5];
  const float* W3  = (const float*)d_in[6];
  const float* b3  = (const float*)d_in[7];
  const float* Wk  = (const float*)d_in[8];
  const float* bk  = (const float*)d_in[9];
  const float* Wq  = (const float*)d_in[10];
  const float* bq  = (const float*)d_in[11];
  const float* Wr  = (const float*)d_in[12];
  const float* br  = (const float*)d_in[13];
  const float* lng = (const float*)d_in[14];
  const float* lnb = (const float*)d_in[15];
  const float* Wf  = (const float*)d_in[16];
  const float* bfv = (const float*)d_in[17];
  float* out = (float*)d_out;

  const int n = NNODES, E = NEDGES;
  char* ws = (char*)d_ws; size_t off = 0;
  auto alloc = [&](size_t bytes)->void*{
    void* p = ws + off; off += (bytes + 255) & ~(size_t)255; return p;
  };
  __half* xh   = (__half*)alloc((size_t)n*128*2);
  float*  xa   = (float*)alloc((size_t)n*128*4);
  __half* h1h  = (__half*)alloc((size_t)n*128*2);
  float*  h1a  = (float*)alloc((size_t)n*128*4);
  float*  h2   = (float*)alloc((size_t)n*256*4);
  __half* h2h  = (__half*)alloc((size_t)n*256*2);
  __half* keysh= (__half*)alloc((size_t)n*256*2);
  __half* querh= (__half*)alloc((size_t)n*256*2);
  float*  hatt = (float*)alloc((size_t)n*256*4);
  __half* hw3h = (__half*)alloc((size_t)n*64*2);
  float*  resid= (float*)alloc((size_t)n*64*4);
  float*  zbuf = (float*)alloc((size_t)n*64*4);
  float*  es   = (float*)alloc((size_t)E*4);
  float*  dinv = (float*)alloc((size_t)n*4);
  float*  Sall = (float*)alloc(256*4);
  int* degc = (int*)alloc((size_t)n*4);
  int* degr = (int*)alloc((size_t)n*4);
  int* ptrc = (int*)alloc((size_t)(n+1)*4);
  int* ptrr = (int*)alloc((size_t)(n+1)*4);
  int* curc = (int*)alloc((size_t)n*4);
  int* curr = (int*)alloc((size_t)n*4);
  int* csrc = (int*)alloc((size_t)E*4);
  int* csri = (int*)alloc((size_t)E*4);
  int* csrd = (int*)alloc((size_t)E*4);
  unsigned* poolu = (unsigned*)alloc(64*4);

  // graph structure
  k_init   <<<dim3((n+255)/256), 256, 0, stream>>>(degc, degr, Sall, poolu, n);
  k_degree <<<dim3(E/256),       256, 0, stream>>>(ei, degc, degr, E);
  k_scan   <<<1, 1024, 0, stream>>>(degc, ptrc, n);
  k_scan   <<<1, 1024, 0, stream>>>(degr, ptrr, n);
  k_prep   <<<dim3((n+255)/256), 256, 0, stream>>>(degc, ptrc, ptrr, dinv, curc, curr, n);
  k_scatter<<<dim3(E/256),       256, 0, stream>>>(ei, curc, curr, csrc, csri, csrd, E);
  k_half   <<<dim3(n*128/256),   256, 0, stream>>>(x, xh, n*128);

  auto gemm = [&](const float* A, const float* W, const float* bias,
                  float* Cf, __half* Ch, int M, int K, int N, int act){
    gemm_bias<<<dim3(M/64, N/64), 256, 0, stream>>>(A, W, bias, Cf, Ch, M, K, N, act);
  };

  // residual = x@Wr + br
  gemm(x, Wr, br, resid, nullptr, n, 128, 64, 0);
  // conv1: (A @ x) @ W1 + b1, leaky  (aggregate-then-transform, exact reassociation)
  k_aggh<<<n, 128, 0, stream>>>(xh, ptrc, csrc, dinv, xa, 128);
  gemm(xa, W1, b1, nullptr, h1h, n, 128, 128, 1);
  // conv2: (A @ h1) @ W2 + b2, leaky — aggregate on 128-wide h1
  k_aggh<<<n, 128, 0, stream>>>(h1h, ptrc, csrc, dinv, h1a, 128);
  gemm(h1a, W2, b2, h2, h2h, n, 128, 256, 1);
  // attention
  gemm(h2, Wk, bk, nullptr, keysh, n, 256, 256, 0);
  gemm(h2, Wq, bq, nullptr, querh, n, 256, 256, 0);
  k_colsum<<<64, 256, 0, stream>>>(h2, Sall, n);
  k_scores<<<dim3(E/4), 256, 0, stream>>>(querh, keysh, csri, csrd, es, E);
  k_attn  <<<n, 256, 0, stream>>>(h2h, Sall, ptrr, csrd, es, hatt, n);
  // conv3 transform (64-wide), then fused agg+residual+LN
  gemm(hatt, W3, nullptr, nullptr, hw3h, n, 256, 64, 0);
  k_z     <<<n, 64, 0, stream>>>(hw3h, b3, ptrc, csrc, dinv, resid, lng, lnb, zbuf);
  k_pool  <<<64, 256, 0, stream>>>(zbuf, poolu, n);
  k_final <<<1, 64, 0, stream>>>(poolu, Wf, bfv, out);
}

// Round 3
// 400.474 us; speedup vs baseline: 1.1302x; 1.0215x over previous
//
#include <hip/hip_runtime.h>
#include <hip/hip_fp16.h>
#include <cstdint>
#include <cstddef>

#define NNODES 8192
#define NEDGES 262144

__device__ __forceinline__ float leaky(float v){ return v > 0.f ? v : 0.01f*v; }

__device__ __forceinline__ unsigned fmap(float f){
  unsigned u = __float_as_uint(f);
  return (u & 0x80000000u) ? ~u : (u | 0x80000000u);
}
__device__ __forceinline__ float funmap(unsigned u){
  return (u & 0x80000000u) ? __uint_as_float(u & 0x7FFFFFFFu) : __uint_as_float(~u);
}

// ---------------- init ----------------
__global__ void k_init(int* degc, int* degr, float* Sall, unsigned* poolu, int n){
  int t = blockIdx.x*blockDim.x + threadIdx.x;
  if (t < n){ degc[t]=0; degr[t]=0; }
  if (t < 256) Sall[t]=0.f;
  if (t < 64) poolu[t]=0u;
}

// ---------------- fp32 -> fp16 ----------------
__global__ void k_half(const float* __restrict__ a, __half* __restrict__ b, int n){
  int t = blockIdx.x*blockDim.x + threadIdx.x;
  if (t < n) b[t] = __float2half(a[t]);
}

// ---------------- degrees ----------------
__global__ void k_degree(const int* __restrict__ ei, int* degc, int* degr, int E){
  int e = blockIdx.x*blockDim.x + threadIdx.x;
  if (e >= E) return;
  atomicAdd(&degc[ei[E+e]], 1);
  atomicAdd(&degr[ei[e]],   1);
}

// ---------------- single-block exclusive scan over n=8192 ----------------
__global__ __launch_bounds__(1024) void k_scan(const int* __restrict__ deg, int* __restrict__ ptr, int n){
  __shared__ int part[1024];
  int t = threadIdx.x;
  const int per = 8;
  int base = t*per;
  int loc[8]; int s = 0;
  #pragma unroll
  for (int q=0;q<per;q++){ loc[q]=s; s += deg[base+q]; }
  part[t]=s; __syncthreads();
  for (int o=1;o<1024;o<<=1){
    int v = (t>=o)? part[t-o] : 0;
    __syncthreads();
    if (t>=o) part[t]+=v;
    __syncthreads();
  }
  int prev = t ? part[t-1] : 0;
  #pragma unroll
  for (int q=0;q<per;q++) ptr[base+q] = prev + loc[q];
  if (t==1023) ptr[n] = part[1023];
}

// ---------------- dinv + cursors ----------------
__global__ void k_prep(const int* __restrict__ degc, const int* __restrict__ ptrc,
                       const int* __restrict__ ptrr,
                       float* dinv, int* curc, int* curr, int n){
  int i = blockIdx.x*blockDim.x + threadIdx.x;
  if (i>=n) return;
  dinv[i] = rsqrtf((float)(degc[i]+1));
  curc[i] = ptrc[i];
  curr[i] = ptrr[i];
}

// ---------------- scatter into two CSRs ----------------
__global__ void k_scatter(const int* __restrict__ ei, int* curc, int* curr,
                          int* csrc, int* csrd, int E){
  int e = blockIdx.x*blockDim.x + threadIdx.x;
  if (e>=E) return;
  int r = ei[e], c = ei[E+e];
  int p1 = atomicAdd(&curc[c],1); csrc[p1] = r;   // GCN: in-neighbors of col c
  int p2 = atomicAdd(&curr[r],1); csrd[p2] = c;   // attention: neighbors of row r
}

// ---------------- 256x256 transpose ----------------
__global__ void k_tr256(const float* __restrict__ A, float* __restrict__ B){
  int o = blockIdx.x*16 + (threadIdx.x & 15);
  int c = blockIdx.y*16 + (threadIdx.x >> 4);
  B[o*256 + c] = A[c*256 + o];
}

// ---------------- small vectors: bqk = Wk@bq, wb = Wq@bk, s0 = bq.bk ----------------
__global__ __launch_bounds__(256) void k_smallvec(const float* __restrict__ Wk,
    const float* __restrict__ Wq, const float* __restrict__ bq,
    const float* __restrict__ bk, float* bqk, float* wb, float* s0p){
  int c = threadIdx.x;
  float a=0.f, b=0.f;
  for (int o=0;o<256;++o){
    a = fmaf(Wk[c*256+o], bq[o], a);
    b = fmaf(Wq[c*256+o], bk[o], b);
  }
  bqk[c]=a; wb[c]=b;
  __shared__ float red[256];
  red[c] = bq[c]*bk[c];
  __syncthreads();
  for (int off=128; off; off>>=1){ if (c<off) red[c]+=red[c+off]; __syncthreads(); }
  if (c==0) s0p[0]=red[0];
}

// ---------------- fp32 tiled GEMM: C = A@W (+bias, +opt leaky), dual fp32/fp16 store ----
__global__ __launch_bounds__(256) void gemm_bias(const float* __restrict__ A,
    const float* __restrict__ W, const float* __restrict__ bias,
    float* __restrict__ Cf, __half* __restrict__ Ch,
    int M, int K, int N, int act){
  __shared__ float As[16][68];
  __shared__ float Ws[16][64];
  int t  = threadIdx.x;
  int m0 = blockIdx.x * 64;
  int n0 = blockIdx.y * 64;
  int tr = t >> 4, tc = t & 15;
  int ar = t >> 2;
  int ak = (t & 3) * 4;
  int wk = t >> 4;
  int wn = (t & 15) * 4;
  float acc[4][4] = {};
  for (int k0 = 0; k0 < K; k0 += 16){
    float4 av = *(const float4*)(A + (size_t)(m0 + ar) * K + k0 + ak);
    float4 wv = *(const float4*)(W + (size_t)(k0 + wk) * N + n0 + wn);
    As[ak+0][ar] = av.x; As[ak+1][ar] = av.y; As[ak+2][ar] = av.z; As[ak+3][ar] = av.w;
    *(float4*)&Ws[wk][wn] = wv;
    __syncthreads();
    #pragma unroll
    for (int kk = 0; kk < 16; ++kk){
      float a[4], w[4];
      *(float4*)a = *(const float4*)&As[kk][tr*4];
      *(float4*)w = *(const float4*)&Ws[kk][tc*4];
      #pragma unroll
      for (int i=0;i<4;i++)
        #pragma unroll
        for (int j=0;j<4;j++)
          acc[i][j] = fmaf(a[i], w[j], acc[i][j]);
    }
    __syncthreads();
  }
  float4 bv = make_float4(0.f,0.f,0.f,0.f);
  if (bias) bv = *(const float4*)(bias + n0 + tc*4);
  #pragma unroll
  for (int i=0;i<4;i++){
    float v0 = acc[i][0]+bv.x, v1 = acc[i][1]+bv.y, v2 = acc[i][2]+bv.z, v3 = acc[i][3]+bv.w;
    if (act){ v0 = leaky(v0); v1 = leaky(v1); v2 = leaky(v2); v3 = leaky(v3); }
    size_t base = (size_t)(m0 + tr*4 + i)*N + n0 + tc*4;
    if (Cf){
      float4 v; v.x=v0; v.y=v1; v.z=v2; v.w=v3;
      *(float4*)(Cf + base) = v;
    }
    if (Ch){
      __half2* hp = (__half2*)(Ch + base);
      hp[0] = __floats2half2_rn(v0, v1);
      hp[1] = __floats2half2_rn(v2, v3);
    }
  }
}

// ---------------- GCN aggregation, F=128: 4 waves split edges, LDS combine ----------------
__global__ __launch_bounds__(256) void k_agg128(const __half* __restrict__ in,
    const int* __restrict__ ptr, const int* __restrict__ src,
    const float* __restrict__ dinv, float* __restrict__ outp){
  int c = blockIdx.x, t = threadIdx.x, w = t>>6, lane = t&63;
  float dc = dinv[c];
  float2 acc = make_float2(0.f, 0.f);
  int e0 = ptr[c], e1 = ptr[c+1];
  for (int e = e0 + w; e < e1; e += 4){
    int r = src[e];
    float2 hv = __half22float2(*(const __half2*)(in + (size_t)r*128 + lane*2));
    float sc = dinv[r];
    acc.x = fmaf(sc, hv.x, acc.x);
    acc.y = fmaf(sc, hv.y, acc.y);
  }
  __shared__ float2 red[4][64];
  red[w][lane] = acc;
  __syncthreads();
  if (w == 0){
    float2 s = red[0][lane];
    float2 b1 = red[1][lane], b2 = red[2][lane], b3 = red[3][lane];
    s.x += b1.x + b2.x + b3.x;
    s.y += b1.y + b2.y + b3.y;
    float2 self = __half22float2(*(const __half2*)(in + (size_t)c*128 + lane*2));
    float2 o;
    o.x = dc*(dc*self.x + s.x);
    o.y = dc*(dc*self.y + s.y);
    *(float2*)(outp + (size_t)c*128 + lane*2) = o;
  }
}

// ---------------- column sums of h2h [n,256] -> Sall[256] ----------------
__global__ void k_colsum(const __half* __restrict__ h2h, float* Sall, int n){
  int f = threadIdx.x;
  float acc = 0.f;
  int r0 = blockIdx.x * 128;
  for (int r = r0; r < r0 + 128; ++r) acc += __half2float(h2h[(size_t)r*256 + f]);
  atomicAdd(&Sall[f], acc);
}

// ---------------- fused attention: scores from qt.h2_j, single h2 gather ----------------
// s_ij = qt_i . h2_j + c_i ;  c_i = h2_i . wb + s0
// hatt[i,f] = (Sall[f] + sum_nbr (exp(s_ij)-1) h2_j[f]) / ((n-k_i) + sum exp(s_ij))
__global__ __launch_bounds__(256) void k_attn2(const __half* __restrict__ h2h,
    const float* __restrict__ qt, const float* __restrict__ Sall,
    const float* __restrict__ wb, const float* __restrict__ s0p,
    const int* __restrict__ ptrr, const int* __restrict__ csrd,
    float* __restrict__ hatt, int n){
  int i = blockIdx.x, t = threadIdx.x, w = t>>6, lane = t&63;
  __shared__ float qtS[256];
  __shared__ __half hS[8][256];
  __shared__ float esS[8];
  __shared__ float wred[4];
  qtS[t] = qt[(size_t)i*256 + t];
  // c_i
  float pv = __half2float(h2h[(size_t)i*256 + t]) * wb[t];
  #pragma unroll
  for (int mm=32; mm; mm>>=1) pv += __shfl_xor(pv, mm, 64);
  if (lane==0) wred[w] = pv;
  __syncthreads();
  float Ei = __expf(wred[0]+wred[1]+wred[2]+wred[3] + s0p[0]);

  int e0 = ptrr[i], e1 = ptrr[i+1];
  float acc = Sall[t];
  float dsum = 0.f;
  for (int eb = e0; eb < e1; eb += 8){
    int m = e1 - eb; if (m > 8) m = 8;
    // stage m rows of h2h into LDS (wave w handles slots w, w+4)
    for (int s = w; s < m; s += 4){
      int j = csrd[eb + s];
      *(uint2*)&hS[s][lane*4] = *(const uint2*)(h2h + (size_t)j*256 + lane*4);
    }
    __syncthreads();
    // dots
    for (int s = w; s < m; s += 4){
      const __half2* hp = (const __half2*)&hS[s][0];
      float2 a = __half22float2(hp[lane*2]);
      float2 b = __half22float2(hp[lane*2+1]);
      float d = qtS[lane*4]*a.x + qtS[lane*4+1]*a.y
              + qtS[lane*4+2]*b.x + qtS[lane*4+3]*b.y;
      #pragma unroll
      for (int mm=32; mm; mm>>=1) d += __shfl_xor(d, mm, 64);
      if (lane==0) esS[s] = __expf(d);
    }
    __syncthreads();
    // accumulate
    for (int s = 0; s < m; ++s){
      float we = Ei * esS[s];
      dsum += we;
      acc = fmaf(we - 1.0f, __half2float(hS[s][t]), acc);
    }
    __syncthreads();
  }
  float den = (float)(n - (e1 - e0)) + dsum;
  hatt[(size_t)i*256 + t] = acc / den;
}

// ---------------- fused conv3 agg + bias + leaky + residual + LayerNorm (4 waves) ----
__global__ __launch_bounds__(256) void k_z256(const __half* __restrict__ hw3h,
    const float* __restrict__ b3, const int* __restrict__ ptrc,
    const int* __restrict__ csrc, const float* __restrict__ dinv,
    const float* __restrict__ resid, const float* __restrict__ lng,
    const float* __restrict__ lnb, float* __restrict__ z){
  int c = blockIdx.x, t = threadIdx.x, w = t>>6, lane = t&63;
  float dc = dinv[c];
  float acc = 0.f;
  int e0 = ptrc[c], e1 = ptrc[c+1];
  for (int e = e0 + w; e < e1; e += 4){
    int r = csrc[e];
    acc = fmaf(dinv[r], __half2float(hw3h[(size_t)r*64 + lane]), acc);
  }
  __shared__ float red[4][64];
  red[w][lane] = acc;
  __syncthreads();
  if (w == 0){
    acc = red[0][lane]+red[1][lane]+red[2][lane]+red[3][lane];
    float self = __half2float(hw3h[(size_t)c*64 + lane]);
    float v = leaky(dc*(dc*self + acc) + b3[lane]) + resid[(size_t)c*64 + lane];
    float s = v;
    #pragma unroll
    for (int mm=32; mm; mm>>=1) s += __shfl_xor(s, mm, 64);
    float mu = s * (1.0f/64.0f);
    float d = v - mu;
    float s2 = d*d;
    #pragma unroll
    for (int mm=32; mm; mm>>=1) s2 += __shfl_xor(s2, mm, 64);
    z[(size_t)c*64 + lane] = d * rsqrtf(s2*(1.0f/64.0f) + 1e-5f) * lng[lane] + lnb[lane];
  }
}

// ---------------- max pool (monotonic uint atomicMax) ----------------
__global__ __launch_bounds__(256) void k_pool(const float* __restrict__ z,
    unsigned* __restrict__ poolu, int n){
  int f = threadIdx.x & 63, rg = threadIdx.x >> 6;
  float m = -3.402823466e38f;
  int r0 = blockIdx.x * 128;
  for (int r = r0 + rg; r < r0 + 128; r += 4) m = fmaxf(m, z[(size_t)r*64 + f]);
  __shared__ float sh[4][64];
  sh[rg][f] = m; __syncthreads();
  if (rg == 0){
    m = fmaxf(fmaxf(sh[0][f],sh[1][f]), fmaxf(sh[2][f],sh[3][f]));
    atomicMax(&poolu[f], fmap(m));
  }
}

// ---------------- final ----------------
__global__ __launch_bounds__(64) void k_final(const unsigned* __restrict__ poolu,
    const float* __restrict__ Wf, const float* __restrict__ bfv, float* __restrict__ out){
  __shared__ float p[64];
  int t = threadIdx.x;
  p[t] = funmap(poolu[t]);
  __syncthreads();
  if (t < 16){
    float acc = bfv[t];
    #pragma unroll
    for (int f=0; f<64; ++f) acc = fmaf(p[f], Wf[f*16 + t], acc);
    out[t] = acc;
  }
}

extern "C" void kernel_launch(void* const* d_in, const int* in_sizes, int n_in,
                              void* d_out, int out_size, void* d_ws, size_t ws_size,
                              hipStream_t stream){
  const float* x   = (const float*)d_in[0];
  const int*   ei  = (const int*)d_in[1];
  const float* W1  = (const float*)d_in[2];
  const float* b1  = (const float*)d_in[3];
  const float* W2  = (const float*)d_in[4];
  const float* b2  = (const float*)d_in[5];
  const float* W3  = (const float*)d_in[6];
  const float* b3  = (const float*)d_in[7];
  const float* Wk  = (const float*)d_in[8];
  const float* bk  = (const float*)d_in[9];
  const float* Wq  = (const float*)d_in[10];
  const float* bq  = (const float*)d_in[11];
  const float* Wr  = (const float*)d_in[12];
  const float* br  = (const float*)d_in[13];
  const float* lng = (const float*)d_in[14];
  const float* lnb = (const float*)d_in[15];
  const float* Wf  = (const float*)d_in[16];
  const float* bfv = (const float*)d_in[17];
  float* out = (float*)d_out;

  const int n = NNODES, E = NEDGES;
  char* ws = (char*)d_ws; size_t off = 0;
  auto alloc = [&](size_t bytes)->void*{
    void* p = ws + off; off += (bytes + 255) & ~(size_t)255; return p;
  };
  __half* xh   = (__half*)alloc((size_t)n*128*2);
  float*  xa   = (float*)alloc((size_t)n*128*4);
  __half* h1h  = (__half*)alloc((size_t)n*128*2);
  float*  h1a  = (float*)alloc((size_t)n*128*4);
  float*  h2   = (float*)alloc((size_t)n*256*4);
  __half* h2h  = (__half*)alloc((size_t)n*256*2);
  float*  qt   = (float*)alloc((size_t)n*256*4);
  float*  hatt = (float*)alloc((size_t)n*256*4);
  __half* hw3h = (__half*)alloc((size_t)n*64*2);
  float*  resid= (float*)alloc((size_t)n*64*4);
  float*  zbuf = (float*)alloc((size_t)n*64*4);
  float*  dinv = (float*)alloc((size_t)n*4);
  float*  Sall = (float*)alloc(256*4);
  float*  Wkt  = (float*)alloc(256*256*4);
  float*  Wqk  = (float*)alloc(256*256*4);
  float*  bqk  = (float*)alloc(256*4);
  float*  wb   = (float*)alloc(256*4);
  float*  s0p  = (float*)alloc(4);
  int* degc = (int*)alloc((size_t)n*4);
  int* degr = (int*)alloc((size_t)n*4);
  int* ptrc = (int*)alloc((size_t)(n+1)*4);
  int* ptrr = (int*)alloc((size_t)(n+1)*4);
  int* curc = (int*)alloc((size_t)n*4);
  int* curr = (int*)alloc((size_t)n*4);
  int* csrc = (int*)alloc((size_t)E*4);
  int* csrd = (int*)alloc((size_t)E*4);
  unsigned* poolu = (unsigned*)alloc(64*4);

  // graph structure
  k_init   <<<dim3((n+255)/256), 256, 0, stream>>>(degc, degr, Sall, poolu, n);
  k_degree <<<dim3(E/256),       256, 0, stream>>>(ei, degc, degr, E);
  k_scan   <<<1, 1024, 0, stream>>>(degc, ptrc, n);
  k_scan   <<<1, 1024, 0, stream>>>(degr, ptrr, n);
  k_prep   <<<dim3((n+255)/256), 256, 0, stream>>>(degc, ptrc, ptrr, dinv, curc, curr, n);
  k_scatter<<<dim3(E/256),       256, 0, stream>>>(ei, curc, curr, csrc, csrd, E);
  k_half   <<<dim3(n*128/256),   256, 0, stream>>>(x, xh, n*128);

  // attention weight precompute: Wqk = Wq @ Wk^T, bqk = Wk@bq, wb = Wq@bk, s0 = bq.bk
  k_tr256   <<<dim3(16,16), 256, 0, stream>>>(Wk, Wkt);
  k_smallvec<<<1, 256, 0, stream>>>(Wk, Wq, bq, bk, bqk, wb, s0p);

  auto gemm = [&](const float* A, const float* W, const float* bias,
                  float* Cf, __half* Ch, int M, int K, int N, int act){
    gemm_bias<<<dim3(M/64, N/64), 256, 0, stream>>>(A, W, bias, Cf, Ch, M, K, N, act);
  };

  gemm(Wq, Wkt, nullptr, Wqk, nullptr, 256, 256, 256, 0);

  // residual = x@Wr + br
  gemm(x, Wr, br, resid, nullptr, n, 128, 64, 0);
  // conv1: leaky((A.x)@W1 + b1)
  k_agg128<<<n, 256, 0, stream>>>(xh, ptrc, csrc, dinv, xa);
  gemm(xa, W1, b1, nullptr, h1h, n, 128, 128, 1);
  // conv2: leaky((A.h1)@W2 + b2)
  k_agg128<<<n, 256, 0, stream>>>(h1h, ptrc, csrc, dinv, h1a);
  gemm(h1a, W2, b2, h2, h2h, n, 128, 256, 1);
  // attention: qt = h2@Wqk + bqk ; fused scores+softmax+aggregate
  gemm(h2, Wqk, bqk, qt, nullptr, n, 256, 256, 0);
  k_colsum<<<64, 256, 0, stream>>>(h2h, Sall, n);
  k_attn2 <<<n, 256, 0, stream>>>(h2h, qt, Sall, wb, s0p, ptrr, csrd, hatt, n);
  // conv3 transform, fused agg+residual+LN
  gemm(hatt, W3, nullptr, nullptr, hw3h, n, 256, 64, 0);
  k_z256  <<<n, 256, 0, stream>>>(hw3h, b3, ptrc, csrc, dinv, resid, lng, lnb, zbuf);
  k_pool  <<<64, 256, 0, stream>>>(zbuf, poolu, n);
  k_final <<<1, 64, 0, stream>>>(poolu, Wf, bfv, out);
}

// Round 4
// 347.064 us; speedup vs baseline: 1.3042x; 1.1539x over previous
//
#include <hip/hip_runtime.h>
#include <hip/hip_fp16.h>
#include <cstdint>
#include <cstddef>

#define NNODES 8192
#define NEDGES 262144

typedef _Float16 f16x8 __attribute__((ext_vector_type(8)));
typedef float    f32x4 __attribute__((ext_vector_type(4)));

__device__ __forceinline__ float leaky(float v){ return v > 0.f ? v : 0.01f*v; }

__device__ __forceinline__ unsigned fmap(float f){
  unsigned u = __float_as_uint(f);
  return (u & 0x80000000u) ? ~u : (u | 0x80000000u);
}
__device__ __forceinline__ float funmap(unsigned u){
  return (u & 0x80000000u) ? __uint_as_float(u & 0x7FFFFFFFu) : __uint_as_float(~u);
}

// ---------------- init ----------------
__global__ void k_init(int* degc, int* degr, float* Sall, unsigned* poolu, int n){
  int t = blockIdx.x*blockDim.x + threadIdx.x;
  if (t < n){ degc[t]=0; degr[t]=0; }
  if (t < 256) Sall[t]=0.f;
  if (t < 64) poolu[t]=0u;
}

// ---------------- fp32 -> fp16 ----------------
__global__ void k_half(const float* __restrict__ a, __half* __restrict__ b, int n){
  int t = blockIdx.x*blockDim.x + threadIdx.x;
  if (t < n) b[t] = __float2half(a[t]);
}

// ---------------- transpose + halve: in[K][N] fp32 -> out[N][K] fp16 ----------------
__global__ void k_trh(const float* __restrict__ in, __half* __restrict__ out, int K, int N){
  int t = blockIdx.x*blockDim.x + threadIdx.x;
  if (t >= K*N) return;
  int nn = t / K, k = t - nn*K;
  out[t] = __float2half(in[k*N + nn]);
}

// ---------------- degrees ----------------
__global__ void k_degree(const int* __restrict__ ei, int* degc, int* degr, int E){
  int e = blockIdx.x*blockDim.x + threadIdx.x;
  if (e >= E) return;
  atomicAdd(&degc[ei[E+e]], 1);
  atomicAdd(&degr[ei[e]],   1);
}

// ---------------- exclusive scans (block 0: degc->ptrc, block 1: degr->ptrr) ----------
__global__ __launch_bounds__(1024) void k_scan(const int* __restrict__ degA,
    const int* __restrict__ degB, int* __restrict__ ptrA, int* __restrict__ ptrB, int n){
  const int* deg = blockIdx.x ? degB : degA;
  int* ptr = blockIdx.x ? ptrB : ptrA;
  __shared__ int part[1024];
  int t = threadIdx.x;
  const int per = 8;
  int base = t*per;
  int loc[8]; int s = 0;
  #pragma unroll
  for (int q=0;q<per;q++){ loc[q]=s; s += deg[base+q]; }
  part[t]=s; __syncthreads();
  for (int o=1;o<1024;o<<=1){
    int v = (t>=o)? part[t-o] : 0;
    __syncthreads();
    if (t>=o) part[t]+=v;
    __syncthreads();
  }
  int prev = t ? part[t-1] : 0;
  #pragma unroll
  for (int q=0;q<per;q++) ptr[base+q] = prev + loc[q];
  if (t==1023) ptr[n] = part[1023];
}

// ---------------- dinv + cursors ----------------
__global__ void k_prep(const int* __restrict__ degc, const int* __restrict__ ptrc,
                       const int* __restrict__ ptrr,
                       float* dinv, int* curc, int* curr, int n){
  int i = blockIdx.x*blockDim.x + threadIdx.x;
  if (i>=n) return;
  dinv[i] = rsqrtf((float)(degc[i]+1));
  curc[i] = ptrc[i];
  curr[i] = ptrr[i];
}

// ---------------- scatter into two CSRs ----------------
__global__ void k_scatter(const int* __restrict__ ei, int* curc, int* curr,
                          int* csrc, int* csrd, int E){
  int e = blockIdx.x*blockDim.x + threadIdx.x;
  if (e>=E) return;
  int r = ei[e], c = ei[E+e];
  int p1 = atomicAdd(&curc[c],1); csrc[p1] = r;   // GCN: in-neighbors of col c
  int p2 = atomicAdd(&curr[r],1); csrd[p2] = c;   // attention: neighbors of row r
}

// ---------------- small vectors: bqk = Wk@bq, wb = Wq@bk, s0 = bq.bk ----------------
__global__ __launch_bounds__(256) void k_smallvec(const float* __restrict__ Wk,
    const float* __restrict__ Wq, const float* __restrict__ bq,
    const float* __restrict__ bk, float* bqk, float* wb, float* s0p){
  int c = threadIdx.x;
  float a=0.f, b=0.f;
  for (int o=0;o<256;++o){
    a = fmaf(Wk[c*256+o], bq[o], a);
    b = fmaf(Wq[c*256+o], bk[o], b);
  }
  bqk[c]=a; wb[c]=b;
  __shared__ float red[256];
  red[c] = bq[c]*bk[c];
  __syncthreads();
  for (int off=128; off; off>>=1){ if (c<off) red[c]+=red[c+off]; __syncthreads(); }
  if (c==0) s0p[0]=red[0];
}

// ---------------- MFMA GEMM: C[M,N] = A[M,K](f16) @ Bt[N,K](f16)^T  (+bias, +leaky)
// 64x64 tile, BK=32, 256 thr (4 waves); wave w -> rows w*16..w*16+15
// frag layouts (m91/m120-verified): A[m=lane&15][k=quad*8+j]; B[k=quad*8+j][n=lane&15];
// C/D: row=quad*4+reg, col=lane&15
__global__ __launch_bounds__(256) void gemm_mfma(const __half* __restrict__ A,
    const __half* __restrict__ Bt, const float* __restrict__ bias,
    float* __restrict__ Cf, __half* __restrict__ Ch,
    int M, int K, int N, int act){
  __shared__ _Float16 As[64][40];   // row stride 40 halves = 80 B -> 2-way bank alias (free)
  __shared__ _Float16 Bs[64][40];
  int t = threadIdx.x, w = t>>6, lane = t&63;
  int m0 = blockIdx.x*64, n0 = blockIdx.y*64;
  int quad = lane>>4, l15 = lane&15;
  int srow = t>>2, soff = (t&3)*8;
  f32x4 acc0 = {0.f,0.f,0.f,0.f}, acc1 = acc0, acc2 = acc0, acc3 = acc0;
  for (int k0 = 0; k0 < K; k0 += 32){
    *(uint4*)&As[srow][soff] = *(const uint4*)(A  + (size_t)(m0+srow)*K + k0 + soff);
    *(uint4*)&Bs[srow][soff] = *(const uint4*)(Bt + (size_t)(n0+srow)*K + k0 + soff);
    __syncthreads();
    f16x8 af = *(const f16x8*)&As[w*16 + l15][quad*8];
    f16x8 b0 = *(const f16x8*)&Bs[ 0 + l15][quad*8];
    f16x8 b1 = *(const f16x8*)&Bs[16 + l15][quad*8];
    f16x8 b2 = *(const f16x8*)&Bs[32 + l15][quad*8];
    f16x8 b3 = *(const f16x8*)&Bs[48 + l15][quad*8];
    acc0 = __builtin_amdgcn_mfma_f32_16x16x32_f16(af, b0, acc0, 0,0,0);
    acc1 = __builtin_amdgcn_mfma_f32_16x16x32_f16(af, b1, acc1, 0,0,0);
    acc2 = __builtin_amdgcn_mfma_f32_16x16x32_f16(af, b2, acc2, 0,0,0);
    acc3 = __builtin_amdgcn_mfma_f32_16x16x32_f16(af, b3, acc3, 0,0,0);
    __syncthreads();
  }
  f32x4 accs[4] = {acc0, acc1, acc2, acc3};
  #pragma unroll
  for (int nt=0; nt<4; ++nt){
    int col = n0 + nt*16 + l15;
    float bv = bias ? bias[col] : 0.f;
    #pragma unroll
    for (int r=0;r<4;r++){
      int row = m0 + w*16 + quad*4 + r;
      float v = accs[nt][r] + bv;
      if (act) v = leaky(v);
      if (Cf) Cf[(size_t)row*N + col] = v;
      if (Ch) Ch[(size_t)row*N + col] = __float2half(v);
    }
  }
}

// ---------------- GCN aggregation, F=128, fp16 out: 4 waves split edges ----------------
__global__ __launch_bounds__(256) void k_agg128(const __half* __restrict__ in,
    const int* __restrict__ ptr, const int* __restrict__ src,
    const float* __restrict__ dinv, __half* __restrict__ outp){
  int c = blockIdx.x, t = threadIdx.x, w = t>>6, lane = t&63;
  float dc = dinv[c];
  float2 acc = make_float2(0.f, 0.f);
  int e0 = ptr[c], e1 = ptr[c+1];
  for (int e = e0 + w; e < e1; e += 4){
    int r = src[e];
    float2 hv = __half22float2(*(const __half2*)(in + (size_t)r*128 + lane*2));
    float sc = dinv[r];
    acc.x = fmaf(sc, hv.x, acc.x);
    acc.y = fmaf(sc, hv.y, acc.y);
  }
  __shared__ float2 red[4][64];
  red[w][lane] = acc;
  __syncthreads();
  if (w == 0){
    float2 s = red[0][lane];
    float2 b1 = red[1][lane], b2 = red[2][lane], b3 = red[3][lane];
    s.x += b1.x + b2.x + b3.x;
    s.y += b1.y + b2.y + b3.y;
    float2 self = __half22float2(*(const __half2*)(in + (size_t)c*128 + lane*2));
    *(__half2*)(outp + (size_t)c*128 + lane*2) =
        __floats2half2_rn(dc*(dc*self.x + s.x), dc*(dc*self.y + s.y));
  }
}

// ---------------- column sums of h2h [n,256] -> Sall[256] ----------------
__global__ void k_colsum(const __half* __restrict__ h2h, float* Sall, int n){
  int f = threadIdx.x;
  float acc = 0.f;
  int r0 = blockIdx.x * 128;
  for (int r = r0; r < r0 + 128; ++r) acc += __half2float(h2h[(size_t)r*256 + f]);
  atomicAdd(&Sall[f], acc);
}

// ---------------- fused attention, wave-per-node, barrier-free ----------------
// s_ij = qt_i.h2_j + c_i ; c_i = h2_i.wb + s0
// hatt[i,f] = (Sall[f] + sum_nbr (exp(s_ij)-1) h2_j[f]) / ((n-k_i) + sum exp(s_ij))
__global__ __launch_bounds__(256) void k_attn3(const __half* __restrict__ h2h,
    const float* __restrict__ qt, const float* __restrict__ Sall,
    const float* __restrict__ wb, const float* __restrict__ s0p,
    const int* __restrict__ ptrr, const int* __restrict__ csrd,
    __half* __restrict__ hatth, int n){
  int w = threadIdx.x>>6, lane = threadIdx.x&63;
  int i = blockIdx.x*4 + w;
  int fo = lane*4;
  float4 q   = *(const float4*)(qt + (size_t)i*256 + fo);
  float4 wbv = *(const float4*)(wb + fo);
  uint2 hiu  = *(const uint2*)(h2h + (size_t)i*256 + fo);
  float2 hia = __half22float2(*(__half2*)&hiu.x);
  float2 hib = __half22float2(*(__half2*)&hiu.y);
  float pv = hia.x*wbv.x + hia.y*wbv.y + hib.x*wbv.z + hib.y*wbv.w;
  #pragma unroll
  for (int mm=32; mm; mm>>=1) pv += __shfl_xor(pv, mm, 64);
  float Ei = __expf(pv + s0p[0]);
  float4 acc = *(const float4*)(Sall + fo);
  float dsum = 0.f;
  int e0 = ptrr[i], e1 = ptrr[i+1];
  uint2 hv; hv.x = 0u; hv.y = 0u;
  if (e0 < e1){
    int j = csrd[e0];
    hv = *(const uint2*)(h2h + (size_t)j*256 + fo);
  }
  for (int e = e0; e < e1; ++e){
    uint2 hvn; hvn.x = 0u; hvn.y = 0u;
    if (e+1 < e1){
      int jn = csrd[e+1];
      hvn = *(const uint2*)(h2h + (size_t)jn*256 + fo);
    }
    float2 ha = __half22float2(*(__half2*)&hv.x);
    float2 hb = __half22float2(*(__half2*)&hv.y);
    float d = q.x*ha.x + q.y*ha.y + q.z*hb.x + q.w*hb.y;
    #pragma unroll
    for (int mm=32; mm; mm>>=1) d += __shfl_xor(d, mm, 64);
    float we = Ei * __expf(d);
    dsum += we;
    we -= 1.f;
    acc.x = fmaf(we, ha.x, acc.x);
    acc.y = fmaf(we, ha.y, acc.y);
    acc.z = fmaf(we, hb.x, acc.z);
    acc.w = fmaf(we, hb.y, acc.w);
    hv = hvn;
  }
  float inv = 1.0f / ((float)(n - (e1 - e0)) + dsum);
  uint2 o;
  *(__half2*)&o.x = __floats2half2_rn(acc.x*inv, acc.y*inv);
  *(__half2*)&o.y = __floats2half2_rn(acc.z*inv, acc.w*inv);
  *(uint2*)(hatth + (size_t)i*256 + fo) = o;
}

// ---------------- fused conv3 agg + bias + leaky + residual + LayerNorm ----------------
__global__ __launch_bounds__(256) void k_z256(const __half* __restrict__ hw3h,
    const float* __restrict__ b3, const int* __restrict__ ptrc,
    const int* __restrict__ csrc, const float* __restrict__ dinv,
    const float* __restrict__ resid, const float* __restrict__ lng,
    const float* __restrict__ lnb, float* __restrict__ z){
  int c = blockIdx.x, t = threadIdx.x, w = t>>6, lane = t&63;
  float dc = dinv[c];
  float acc = 0.f;
  int e0 = ptrc[c], e1 = ptrc[c+1];
  for (int e = e0 + w; e < e1; e += 4){
    int r = csrc[e];
    acc = fmaf(dinv[r], __half2float(hw3h[(size_t)r*64 + lane]), acc);
  }
  __shared__ float red[4][64];
  red[w][lane] = acc;
  __syncthreads();
  if (w == 0){
    acc = red[0][lane]+red[1][lane]+red[2][lane]+red[3][lane];
    float self = __half2float(hw3h[(size_t)c*64 + lane]);
    float v = leaky(dc*(dc*self + acc) + b3[lane]) + resid[(size_t)c*64 + lane];
    float s = v;
    #pragma unroll
    for (int mm=32; mm; mm>>=1) s += __shfl_xor(s, mm, 64);
    float mu = s * (1.0f/64.0f);
    float d = v - mu;
    float s2 = d*d;
    #pragma unroll
    for (int mm=32; mm; mm>>=1) s2 += __shfl_xor(s2, mm, 64);
    z[(size_t)c*64 + lane] = d * rsqrtf(s2*(1.0f/64.0f) + 1e-5f) * lng[lane] + lnb[lane];
  }
}

// ---------------- max pool ----------------
__global__ __launch_bounds__(256) void k_pool(const float* __restrict__ z,
    unsigned* __restrict__ poolu, int n){
  int f = threadIdx.x & 63, rg = threadIdx.x >> 6;
  float m = -3.402823466e38f;
  int r0 = blockIdx.x * 128;
  for (int r = r0 + rg; r < r0 + 128; r += 4) m = fmaxf(m, z[(size_t)r*64 + f]);
  __shared__ float sh[4][64];
  sh[rg][f] = m; __syncthreads();
  if (rg == 0){
    m = fmaxf(fmaxf(sh[0][f],sh[1][f]), fmaxf(sh[2][f],sh[3][f]));
    atomicMax(&poolu[f], fmap(m));
  }
}

// ---------------- final ----------------
__global__ __launch_bounds__(64) void k_final(const unsigned* __restrict__ poolu,
    const float* __restrict__ Wf, const float* __restrict__ bfv, float* __restrict__ out){
  __shared__ float p[64];
  int t = threadIdx.x;
  p[t] = funmap(poolu[t]);
  __syncthreads();
  if (t < 16){
    float acc = bfv[t];
    #pragma unroll
    for (int f=0; f<64; ++f) acc = fmaf(p[f], Wf[f*16 + t], acc);
    out[t] = acc;
  }
}

extern "C" void kernel_launch(void* const* d_in, const int* in_sizes, int n_in,
                              void* d_out, int out_size, void* d_ws, size_t ws_size,
                              hipStream_t stream){
  const float* x   = (const float*)d_in[0];
  const int*   ei  = (const int*)d_in[1];
  const float* W1  = (const float*)d_in[2];
  const float* b1  = (const float*)d_in[3];
  const float* W2  = (const float*)d_in[4];
  const float* b2  = (const float*)d_in[5];
  const float* W3  = (const float*)d_in[6];
  const float* b3  = (const float*)d_in[7];
  const float* Wk  = (const float*)d_in[8];
  const float* bk  = (const float*)d_in[9];
  const float* Wq  = (const float*)d_in[10];
  const float* bq  = (const float*)d_in[11];
  const float* Wr  = (const float*)d_in[12];
  const float* br  = (const float*)d_in[13];
  const float* lng = (const float*)d_in[14];
  const float* lnb = (const float*)d_in[15];
  const float* Wf  = (const float*)d_in[16];
  const float* bfv = (const float*)d_in[17];
  float* out = (float*)d_out;

  const int n = NNODES, E = NEDGES;
  char* ws = (char*)d_ws; size_t off = 0;
  auto alloc = [&](size_t bytes)->void*{
    void* p = ws + off; off += (bytes + 255) & ~(size_t)255; return p;
  };
  __half* xh   = (__half*)alloc((size_t)n*128*2);
  __half* xah  = (__half*)alloc((size_t)n*128*2);
  __half* h1h  = (__half*)alloc((size_t)n*128*2);
  __half* h1ah = (__half*)alloc((size_t)n*128*2);
  __half* h2h  = (__half*)alloc((size_t)n*256*2);
  float*  qt   = (float*)alloc((size_t)n*256*4);
  __half* hatth= (__half*)alloc((size_t)n*256*2);
  __half* hw3h = (__half*)alloc((size_t)n*64*2);
  float*  resid= (float*)alloc((size_t)n*64*4);
  float*  zbuf = (float*)alloc((size_t)n*64*4);
  float*  dinv = (float*)alloc((size_t)n*4);
  float*  Sall = (float*)alloc(256*4);
  __half* Wqh  = (__half*)alloc(256*256*2);
  __half* Wkh  = (__half*)alloc(256*256*2);
  float*  Wqk  = (float*)alloc(256*256*4);
  __half* Wqkt = (__half*)alloc(256*256*2);
  __half* Wrt  = (__half*)alloc(128*64*2);
  __half* W1t  = (__half*)alloc(128*128*2);
  __half* W2t  = (__half*)alloc(128*256*2);
  __half* W3t  = (__half*)alloc(256*64*2);
  float*  bqk  = (float*)alloc(256*4);
  float*  wb   = (float*)alloc(256*4);
  float*  s0p  = (float*)alloc(4);
  int* degc = (int*)alloc((size_t)n*4);
  int* degr = (int*)alloc((size_t)n*4);
  int* ptrc = (int*)alloc((size_t)(n+1)*4);
  int* ptrr = (int*)alloc((size_t)(n+1)*4);
  int* curc = (int*)alloc((size_t)n*4);
  int* curr = (int*)alloc((size_t)n*4);
  int* csrc = (int*)alloc((size_t)E*4);
  int* csrd = (int*)alloc((size_t)E*4);
  unsigned* poolu = (unsigned*)alloc(64*4);

  // graph structure
  k_init   <<<dim3((n+255)/256), 256, 0, stream>>>(degc, degr, Sall, poolu, n);
  k_degree <<<dim3(E/256),       256, 0, stream>>>(ei, degc, degr, E);
  k_scan   <<<2, 1024, 0, stream>>>(degc, degr, ptrc, ptrr, n);
  k_prep   <<<dim3((n+255)/256), 256, 0, stream>>>(degc, ptrc, ptrr, dinv, curc, curr, n);
  k_scatter<<<dim3(E/256),       256, 0, stream>>>(ei, curc, curr, csrc, csrd, E);

  // fp16 conversions & weight transposes
  k_half<<<dim3(n*128/256), 256, 0, stream>>>(x, xh, n*128);
  k_half<<<dim3(256), 256, 0, stream>>>(Wq, Wqh, 256*256);
  k_half<<<dim3(256), 256, 0, stream>>>(Wk, Wkh, 256*256);
  k_trh <<<dim3(32),  256, 0, stream>>>(Wr, Wrt, 128, 64);
  k_trh <<<dim3(64),  256, 0, stream>>>(W1, W1t, 128, 128);
  k_trh <<<dim3(128), 256, 0, stream>>>(W2, W2t, 128, 256);
  k_trh <<<dim3(64),  256, 0, stream>>>(W3, W3t, 256, 64);
  k_smallvec<<<1, 256, 0, stream>>>(Wk, Wq, bq, bk, bqk, wb, s0p);

  auto gemm = [&](const __half* A, const __half* Bt, const float* bias,
                  float* Cf, __half* Ch, int M, int K, int N, int act){
    gemm_mfma<<<dim3(M/64, N/64), 256, 0, stream>>>(A, Bt, bias, Cf, Ch, M, K, N, act);
  };

  // Wqk = Wq @ Wk^T  (Bt = Wk directly), then transpose for qt gemm
  gemm(Wqh, Wkh, nullptr, Wqk, nullptr, 256, 256, 256, 0);
  k_trh <<<dim3(256), 256, 0, stream>>>(Wqk, Wqkt, 256, 256);

  // residual = x@Wr + br
  gemm(xh, Wrt, br, resid, nullptr, n, 128, 64, 0);
  // conv1: leaky((A.x)@W1 + b1)
  k_agg128<<<n, 256, 0, stream>>>(xh, ptrc, csrc, dinv, xah);
  gemm(xah, W1t, b1, nullptr, h1h, n, 128, 128, 1);
  // conv2: leaky((A.h1)@W2 + b2)
  k_agg128<<<n, 256, 0, stream>>>(h1h, ptrc, csrc, dinv, h1ah);
  gemm(h1ah, W2t, b2, nullptr, h2h, n, 128, 256, 1);
  // attention: qt = h2@Wqk + bqk ; fused wave-per-node scores+softmax+aggregate
  gemm(h2h, Wqkt, bqk, qt, nullptr, n, 256, 256, 0);
  k_colsum<<<64, 256, 0, stream>>>(h2h, Sall, n);
  k_attn3 <<<n/4, 256, 0, stream>>>(h2h, qt, Sall, wb, s0p, ptrr, csrd, hatth, n);
  // conv3 transform, fused agg+residual+LN
  gemm(hatth, W3t, nullptr, nullptr, hw3h, n, 256, 64, 0);
  k_z256  <<<n, 256, 0, stream>>>(hw3h, b3, ptrc, csrc, dinv, resid, lng, lnb, zbuf);
  k_pool  <<<64, 256, 0, stream>>>(zbuf, poolu, n);
  k_final <<<1, 64, 0, stream>>>(poolu, Wf, bfv, out);
}

// Round 5
// 325.140 us; speedup vs baseline: 1.3921x; 1.0674x over previous
//
#include <hip/hip_runtime.h>
#include <hip/hip_fp16.h>
#include <cstdint>
#include <cstddef>

#define NNODES 8192
#define NEDGES 262144

typedef _Float16 f16x8 __attribute__((ext_vector_type(8)));
typedef float    f32x4 __attribute__((ext_vector_type(4)));

__device__ __forceinline__ float leaky(float v){ return v > 0.f ? v : 0.01f*v; }

__device__ __forceinline__ unsigned fmap(float f){
  unsigned u = __float_as_uint(f);
  return (u & 0x80000000u) ? ~u : (u | 0x80000000u);
}
__device__ __forceinline__ float funmap(unsigned u){
  return (u & 0x80000000u) ? __uint_as_float(u & 0x7FFFFFFFu) : __uint_as_float(~u);
}

// ================= k_pre: all conversions / transposes / zeroing / small vectors =======
// block ranges:
//  [0,4096)      : x -> xh (fp16), 1048576 elems
//  [4096,4352)   : Wq -> Wqh
//  [4352,4608)   : Wk -> Wkh
//  [4608,4640)   : Wr -> Wrt  (transpose 128x64)
//  [4640,4704)   : W1 -> W1t  (128x128)
//  [4704,4832)   : W2 -> W2t  (128x256)
//  [4832,4896)   : W3 -> W3t  (256x64)
//  4896          : smallvec: bqk = Wk@bq, wb = Wq@bk, s0 = bq.bk
//  [4897,4961)   : zero degc, degr
//  4961          : zero sw3, poolu
__global__ __launch_bounds__(256) void k_pre(
    const float* __restrict__ x, const float* __restrict__ Wq, const float* __restrict__ Wk,
    const float* __restrict__ Wr, const float* __restrict__ W1, const float* __restrict__ W2,
    const float* __restrict__ W3, const float* __restrict__ bq, const float* __restrict__ bk,
    __half* xh, __half* Wqh, __half* Wkh, __half* Wrt, __half* W1t, __half* W2t, __half* W3t,
    float* bqk, float* wb, float* s0p,
    int* degc, int* degr, float* sw3, unsigned* poolu){
  int b = blockIdx.x, t = threadIdx.x;
  if (b < 4096){
    int idx = b*256 + t;
    xh[idx] = __float2half(x[idx]);
  } else if (b < 4352){
    int idx = (b-4096)*256 + t;
    Wqh[idx] = __float2half(Wq[idx]);
  } else if (b < 4608){
    int idx = (b-4352)*256 + t;
    Wkh[idx] = __float2half(Wk[idx]);
  } else if (b < 4640){         // Wr[128][64] -> Wrt[64][128]
    int idx = (b-4608)*256 + t;
    int nn = idx >> 7, k = idx & 127;
    Wrt[idx] = __float2half(Wr[k*64 + nn]);
  } else if (b < 4704){         // W1[128][128] -> W1t[128][128]
    int idx = (b-4640)*256 + t;
    int nn = idx >> 7, k = idx & 127;
    W1t[idx] = __float2half(W1[k*128 + nn]);
  } else if (b < 4832){         // W2[128][256] -> W2t[256][128]
    int idx = (b-4704)*256 + t;
    int nn = idx >> 7, k = idx & 127;
    W2t[idx] = __float2half(W2[k*256 + nn]);
  } else if (b < 4896){         // W3[256][64] -> W3t[64][256]
    int idx = (b-4832)*256 + t;
    int nn = idx >> 8, k = idx & 255;
    W3t[idx] = __float2half(W3[k*64 + nn]);
  } else if (b == 4896){
    int c = t;
    float a=0.f, bb=0.f;
    for (int o=0;o<256;++o){
      a  = fmaf(Wk[c*256+o], bq[o], a);
      bb = fmaf(Wq[c*256+o], bk[o], bb);
    }
    bqk[c]=a; wb[c]=bb;
    __shared__ float red[256];
    red[c] = bq[c]*bk[c];
    __syncthreads();
    for (int off=128; off; off>>=1){ if (c<off) red[c]+=red[c+off]; __syncthreads(); }
    if (c==0) s0p[0]=red[0];
  } else if (b < 4961){
    int idx = (b-4897)*256 + t;
    if (idx < 8192) degc[idx]=0; else degr[idx-8192]=0;
  } else {
    if (t < 64){ sw3[t]=0.f; poolu[t]=0u; }
  }
}

// ---------------- degrees ----------------
__global__ void k_degree(const int* __restrict__ ei, int* degc, int* degr, int E){
  int e = blockIdx.x*blockDim.x + threadIdx.x;
  if (e >= E) return;
  atomicAdd(&degc[ei[E+e]], 1);
  atomicAdd(&degr[ei[e]],   1);
}

// -------- exclusive scans + prep fused (block 0: degc->ptrc,curc,dinv; block 1: degr->ptrr,curr)
__global__ __launch_bounds__(1024) void k_scan(const int* __restrict__ degc,
    const int* __restrict__ degr, int* __restrict__ ptrc, int* __restrict__ ptrr,
    int* __restrict__ curc, int* __restrict__ curr, float* __restrict__ dinv, int n){
  const int* deg = blockIdx.x ? degr : degc;
  int* ptr = blockIdx.x ? ptrr : ptrc;
  int* cur = blockIdx.x ? curr : curc;
  __shared__ int part[1024];
  int t = threadIdx.x;
  const int per = 8;
  int base = t*per;
  int dv[8]; int loc[8]; int s = 0;
  #pragma unroll
  for (int q=0;q<per;q++){ dv[q]=deg[base+q]; loc[q]=s; s += dv[q]; }
  part[t]=s; __syncthreads();
  for (int o=1;o<1024;o<<=1){
    int v = (t>=o)? part[t-o] : 0;
    __syncthreads();
    if (t>=o) part[t]+=v;
    __syncthreads();
  }
  int prev = t ? part[t-1] : 0;
  #pragma unroll
  for (int q=0;q<per;q++){
    int p = prev + loc[q];
    ptr[base+q] = p;
    cur[base+q] = p;
    if (!blockIdx.x) dinv[base+q] = rsqrtf((float)(dv[q]+1));
  }
  if (t==1023) ptr[n] = part[1023];
}

// ---------------- scatter into two CSRs ----------------
__global__ void k_scatter(const int* __restrict__ ei, int* curc, int* curr,
                          int* csrc, int* csrd, int E){
  int e = blockIdx.x*blockDim.x + threadIdx.x;
  if (e>=E) return;
  int r = ei[e], c = ei[E+e];
  int p1 = atomicAdd(&curc[c],1); csrc[p1] = r;   // GCN: in-neighbors of col c
  int p2 = atomicAdd(&curr[r],1); csrd[p2] = c;   // attention: neighbors of row r
}

// ---------------- MFMA GEMM: C[M,N] = A[M,K](f16) @ Bt[N,K](f16)^T  (+bias, +leaky)
// optional csum: accumulates column sums of C (pre-bias/act == post here since used w/o both)
__global__ __launch_bounds__(256) void gemm_mfma(const __half* __restrict__ A,
    const __half* __restrict__ Bt, const float* __restrict__ bias,
    float* __restrict__ Cf, __half* __restrict__ Ch, float* __restrict__ csum,
    int M, int K, int N, int act){
  __shared__ _Float16 As[64][40];   // stride 40 halves = 80B -> 2-way bank alias (free)
  __shared__ _Float16 Bs[64][40];
  int t = threadIdx.x, w = t>>6, lane = t&63;
  int m0 = blockIdx.x*64, n0 = blockIdx.y*64;
  int quad = lane>>4, l15 = lane&15;
  int srow = t>>2, soff = (t&3)*8;
  f32x4 acc0 = {0.f,0.f,0.f,0.f}, acc1 = acc0, acc2 = acc0, acc3 = acc0;
  for (int k0 = 0; k0 < K; k0 += 32){
    *(uint4*)&As[srow][soff] = *(const uint4*)(A  + (size_t)(m0+srow)*K + k0 + soff);
    *(uint4*)&Bs[srow][soff] = *(const uint4*)(Bt + (size_t)(n0+srow)*K + k0 + soff);
    __syncthreads();
    f16x8 af = *(const f16x8*)&As[w*16 + l15][quad*8];
    f16x8 b0 = *(const f16x8*)&Bs[ 0 + l15][quad*8];
    f16x8 b1 = *(const f16x8*)&Bs[16 + l15][quad*8];
    f16x8 b2 = *(const f16x8*)&Bs[32 + l15][quad*8];
    f16x8 b3 = *(const f16x8*)&Bs[48 + l15][quad*8];
    acc0 = __builtin_amdgcn_mfma_f32_16x16x32_f16(af, b0, acc0, 0,0,0);
    acc1 = __builtin_amdgcn_mfma_f32_16x16x32_f16(af, b1, acc1, 0,0,0);
    acc2 = __builtin_amdgcn_mfma_f32_16x16x32_f16(af, b2, acc2, 0,0,0);
    acc3 = __builtin_amdgcn_mfma_f32_16x16x32_f16(af, b3, acc3, 0,0,0);
    __syncthreads();
  }
  f32x4 accs[4] = {acc0, acc1, acc2, acc3};
  if (csum){
    __shared__ float cs[64];
    if (t < 64) cs[t] = 0.f;
    __syncthreads();
    #pragma unroll
    for (int nt=0; nt<4; ++nt){
      float p = accs[nt][0]+accs[nt][1]+accs[nt][2]+accs[nt][3];
      atomicAdd(&cs[nt*16 + l15], p);
    }
    __syncthreads();
    if (t < 64) atomicAdd(&csum[n0 + t], cs[t]);
  }
  #pragma unroll
  for (int nt=0; nt<4; ++nt){
    int col = n0 + nt*16 + l15;
    float bv = bias ? bias[col] : 0.f;
    #pragma unroll
    for (int r=0;r<4;r++){
      int row = m0 + w*16 + quad*4 + r;
      float v = accs[nt][r] + bv;
      if (act) v = leaky(v);
      if (Cf) Cf[(size_t)row*N + col] = v;
      if (Ch) Ch[(size_t)row*N + col] = __float2half(v);
    }
  }
}

// ---------------- GCN aggregation, F=128, fp16 in/out: 4 waves split edges --------------
__global__ __launch_bounds__(256) void k_agg128(const __half* __restrict__ in,
    const int* __restrict__ ptr, const int* __restrict__ src,
    const float* __restrict__ dinv, __half* __restrict__ outp){
  int c = blockIdx.x, t = threadIdx.x, w = t>>6, lane = t&63;
  float dc = dinv[c];
  float2 acc = make_float2(0.f, 0.f);
  int e0 = ptr[c], e1 = ptr[c+1];
  for (int e = e0 + w; e < e1; e += 4){
    int r = src[e];
    float2 hv = __half22float2(*(const __half2*)(in + (size_t)r*128 + lane*2));
    float sc = dinv[r];
    acc.x = fmaf(sc, hv.x, acc.x);
    acc.y = fmaf(sc, hv.y, acc.y);
  }
  __shared__ float2 red[4][64];
  red[w][lane] = acc;
  __syncthreads();
  if (w == 0){
    float2 s = red[0][lane];
    float2 b1 = red[1][lane], b2 = red[2][lane], b3 = red[3][lane];
    s.x += b1.x + b2.x + b3.x;
    s.y += b1.y + b2.y + b3.y;
    float2 self = __half22float2(*(const __half2*)(in + (size_t)c*128 + lane*2));
    *(__half2*)(outp + (size_t)c*128 + lane*2) =
        __floats2half2_rn(dc*(dc*self.x + s.x), dc*(dc*self.y + s.y));
  }
}

// ---------------- fused attention in 64-dim projected space, wave-per-node --------------
// s_ij = qt_i.h2_j + c_i ; c_i = h2_i.wb + s0 ;  g = h2@W3 ; sw3 = colsum(g)
// hw3[i,f] = (sw3[f] + sum_nbr (exp(s_ij)-1) g_j[f]) / ((n-k_i) + sum exp(s_ij))
__global__ __launch_bounds__(256) void k_attn4(const __half* __restrict__ h2h,
    const __half* __restrict__ qth, const __half* __restrict__ gh,
    const float* __restrict__ sw3, const float* __restrict__ wb,
    const float* __restrict__ s0p, const int* __restrict__ ptrr,
    const int* __restrict__ csrd, __half* __restrict__ hw3h, int n){
  int w = threadIdx.x>>6, lane = threadIdx.x&63;
  int i = blockIdx.x*4 + w;
  int fo = lane*4;
  uint2 qtu = *(const uint2*)(qth + (size_t)i*256 + fo);
  float2 qa = __half22float2(*(__half2*)&qtu.x);
  float2 qb = __half22float2(*(__half2*)&qtu.y);
  float4 wbv = *(const float4*)(wb + fo);
  uint2 hiu  = *(const uint2*)(h2h + (size_t)i*256 + fo);
  float2 hia = __half22float2(*(__half2*)&hiu.x);
  float2 hib = __half22float2(*(__half2*)&hiu.y);
  float pv = hia.x*wbv.x + hia.y*wbv.y + hib.x*wbv.z + hib.y*wbv.w;
  #pragma unroll
  for (int mm=32; mm; mm>>=1) pv += __shfl_xor(pv, mm, 64);
  float Ei = __expf(pv + s0p[0]);
  float acc = 0.f, dsum = 0.f;
  int e0 = ptrr[i], e1 = ptrr[i+1];
  uint2 hv; hv.x=0u; hv.y=0u;
  float gv = 0.f;
  if (e0 < e1){
    int j = csrd[e0];
    hv = *(const uint2*)(h2h + (size_t)j*256 + fo);
    gv = __half2float(gh[(size_t)j*64 + lane]);
  }
  for (int e = e0; e < e1; ++e){
    uint2 hvn; hvn.x=0u; hvn.y=0u;
    float gvn = 0.f;
    if (e+1 < e1){
      int jn = csrd[e+1];
      hvn = *(const uint2*)(h2h + (size_t)jn*256 + fo);
      gvn = __half2float(gh[(size_t)jn*64 + lane]);
    }
    float2 ha = __half22float2(*(__half2*)&hv.x);
    float2 hb = __half22float2(*(__half2*)&hv.y);
    float d = qa.x*ha.x + qa.y*ha.y + qb.x*hb.x + qb.y*hb.y;
    #pragma unroll
    for (int mm=32; mm; mm>>=1) d += __shfl_xor(d, mm, 64);
    float we = Ei * __expf(d);
    dsum += we;
    acc = fmaf(we - 1.f, gv, acc);
    hv = hvn; gv = gvn;
  }
  float den = (float)(n - (e1 - e0)) + dsum;
  hw3h[(size_t)i*64 + lane] = __float2half((sw3[lane] + acc) / den);
}

// ---------------- fused conv3 agg + bias + leaky + residual + LayerNorm -> z fp16 -------
__global__ __launch_bounds__(256) void k_z256(const __half* __restrict__ hw3h,
    const float* __restrict__ b3, const int* __restrict__ ptrc,
    const int* __restrict__ csrc, const float* __restrict__ dinv,
    const float* __restrict__ resid, const float* __restrict__ lng,
    const float* __restrict__ lnb, __half* __restrict__ zh){
  int c = blockIdx.x, t = threadIdx.x, w = t>>6, lane = t&63;
  float dc = dinv[c];
  float acc = 0.f;
  int e0 = ptrc[c], e1 = ptrc[c+1];
  for (int e = e0 + w; e < e1; e += 4){
    int r = csrc[e];
    acc = fmaf(dinv[r], __half2float(hw3h[(size_t)r*64 + lane]), acc);
  }
  __shared__ float red[4][64];
  red[w][lane] = acc;
  __syncthreads();
  if (w == 0){
    acc = red[0][lane]+red[1][lane]+red[2][lane]+red[3][lane];
    float self = __half2float(hw3h[(size_t)c*64 + lane]);
    float v = leaky(dc*(dc*self + acc) + b3[lane]) + resid[(size_t)c*64 + lane];
    float s = v;
    #pragma unroll
    for (int mm=32; mm; mm>>=1) s += __shfl_xor(s, mm, 64);
    float mu = s * (1.0f/64.0f);
    float d = v - mu;
    float s2 = d*d;
    #pragma unroll
    for (int mm=32; mm; mm>>=1) s2 += __shfl_xor(s2, mm, 64);
    zh[(size_t)c*64 + lane] =
        __float2half(d * rsqrtf(s2*(1.0f/64.0f) + 1e-5f) * lng[lane] + lnb[lane]);
  }
}

// ---------------- max pool (fp16 in, monotonic uint atomicMax) ----------------
__global__ __launch_bounds__(256) void k_pool(const __half* __restrict__ zh,
    unsigned* __restrict__ poolu, int n){
  int f = threadIdx.x & 63, rg = threadIdx.x >> 6;
  float m = -3.402823466e38f;
  int r0 = blockIdx.x * 128;
  for (int r = r0 + rg; r < r0 + 128; r += 4)
    m = fmaxf(m, __half2float(zh[(size_t)r*64 + f]));
  __shared__ float sh[4][64];
  sh[rg][f] = m; __syncthreads();
  if (rg == 0){
    m = fmaxf(fmaxf(sh[0][f],sh[1][f]), fmaxf(sh[2][f],sh[3][f]));
    atomicMax(&poolu[f], fmap(m));
  }
}

// ---------------- final ----------------
__global__ __launch_bounds__(64) void k_final(const unsigned* __restrict__ poolu,
    const float* __restrict__ Wf, const float* __restrict__ bfv, float* __restrict__ out){
  __shared__ float p[64];
  int t = threadIdx.x;
  p[t] = funmap(poolu[t]);
  __syncthreads();
  if (t < 16){
    float acc = bfv[t];
    #pragma unroll
    for (int f=0; f<64; ++f) acc = fmaf(p[f], Wf[f*16 + t], acc);
    out[t] = acc;
  }
}

extern "C" void kernel_launch(void* const* d_in, const int* in_sizes, int n_in,
                              void* d_out, int out_size, void* d_ws, size_t ws_size,
                              hipStream_t stream){
  const float* x   = (const float*)d_in[0];
  const int*   ei  = (const int*)d_in[1];
  const float* W1  = (const float*)d_in[2];
  const float* b1  = (const float*)d_in[3];
  const float* W2  = (const float*)d_in[4];
  const float* b2  = (const float*)d_in[5];
  const float* W3  = (const float*)d_in[6];
  const float* b3  = (const float*)d_in[7];
  const float* Wk  = (const float*)d_in[8];
  const float* bk  = (const float*)d_in[9];
  const float* Wq  = (const float*)d_in[10];
  const float* bq  = (const float*)d_in[11];
  const float* Wr  = (const float*)d_in[12];
  const float* br  = (const float*)d_in[13];
  const float* lng = (const float*)d_in[14];
  const float* lnb = (const float*)d_in[15];
  const float* Wf  = (const float*)d_in[16];
  const float* bfv = (const float*)d_in[17];
  float* out = (float*)d_out;

  const int n = NNODES, E = NEDGES;
  char* ws = (char*)d_ws; size_t off = 0;
  auto alloc = [&](size_t bytes)->void*{
    void* p = ws + off; off += (bytes + 255) & ~(size_t)255; return p;
  };
  __half* xh   = (__half*)alloc((size_t)n*128*2);
  __half* xah  = (__half*)alloc((size_t)n*128*2);
  __half* h1h  = (__half*)alloc((size_t)n*128*2);
  __half* h1ah = (__half*)alloc((size_t)n*128*2);
  __half* h2h  = (__half*)alloc((size_t)n*256*2);
  __half* qth  = (__half*)alloc((size_t)n*256*2);
  __half* gh   = (__half*)alloc((size_t)n*64*2);
  __half* hw3h = (__half*)alloc((size_t)n*64*2);
  float*  resid= (float*)alloc((size_t)n*64*4);
  __half* zh   = (__half*)alloc((size_t)n*64*2);
  float*  dinv = (float*)alloc((size_t)n*4);
  float*  sw3  = (float*)alloc(64*4);
  __half* Wqh  = (__half*)alloc(256*256*2);
  __half* Wkh  = (__half*)alloc(256*256*2);
  __half* Wqkt = (__half*)alloc(256*256*2);
  __half* Wrt  = (__half*)alloc(128*64*2);
  __half* W1t  = (__half*)alloc(128*128*2);
  __half* W2t  = (__half*)alloc(128*256*2);
  __half* W3t  = (__half*)alloc(256*64*2);
  float*  bqk  = (float*)alloc(256*4);
  float*  wb   = (float*)alloc(256*4);
  float*  s0p  = (float*)alloc(4);
  int* degc = (int*)alloc((size_t)n*4);
  int* degr = (int*)alloc((size_t)n*4);
  int* ptrc = (int*)alloc((size_t)(n+1)*4);
  int* ptrr = (int*)alloc((size_t)(n+1)*4);
  int* curc = (int*)alloc((size_t)n*4);
  int* curr = (int*)alloc((size_t)n*4);
  int* csrc = (int*)alloc((size_t)E*4);
  int* csrd = (int*)alloc((size_t)E*4);
  unsigned* poolu = (unsigned*)alloc(64*4);

  // 1: all conversions, transposes, zeroing, small vectors
  k_pre<<<dim3(4962), 256, 0, stream>>>(x, Wq, Wk, Wr, W1, W2, W3, bq, bk,
      xh, Wqh, Wkh, Wrt, W1t, W2t, W3t, bqk, wb, s0p, degc, degr, sw3, poolu);
  // 2-4: graph structure
  k_degree <<<dim3(E/256), 256, 0, stream>>>(ei, degc, degr, E);
  k_scan   <<<2, 1024, 0, stream>>>(degc, degr, ptrc, ptrr, curc, curr, dinv, n);
  k_scatter<<<dim3(E/256), 256, 0, stream>>>(ei, curc, curr, csrc, csrd, E);

  auto gemm = [&](const __half* A, const __half* Bt, const float* bias,
                  float* Cf, __half* Ch, float* csum, int M, int K, int N, int act){
    gemm_mfma<<<dim3(M/64, N/64), 256, 0, stream>>>(A, Bt, bias, Cf, Ch, csum, M, K, N, act);
  };

  // 5: Wqkt[n][k] = (Wq@Wk^T)^T = Wk@Wq^T, fp16
  gemm(Wkh, Wqh, nullptr, nullptr, Wqkt, nullptr, 256, 256, 256, 0);
  // 6: residual = x@Wr + br (fp32)
  gemm(xh, Wrt, br, resid, nullptr, nullptr, n, 128, 64, 0);
  // 7-8: conv1 = leaky((A.x)@W1 + b1)
  k_agg128<<<n, 256, 0, stream>>>(xh, ptrc, csrc, dinv, xah);
  gemm(xah, W1t, b1, nullptr, h1h, nullptr, n, 128, 128, 1);
  // 9-10: conv2 = leaky((A.h1)@W2 + b2)
  k_agg128<<<n, 256, 0, stream>>>(h1h, ptrc, csrc, dinv, h1ah);
  gemm(h1ah, W2t, b2, nullptr, h2h, nullptr, n, 128, 256, 1);
  // 11: G = h2@W3 (fp16) + colsum -> sw3
  gemm(h2h, W3t, nullptr, nullptr, gh, sw3, n, 256, 64, 0);
  // 12: qt = h2@Wqk + bqk (fp16)
  gemm(h2h, Wqkt, bqk, nullptr, qth, nullptr, n, 256, 256, 0);
  // 13: fused attention -> hw3h directly (projected 64-dim)
  k_attn4<<<n/4, 256, 0, stream>>>(h2h, qth, gh, sw3, wb, s0p, ptrr, csrd, hw3h, n);
  // 14: conv3 agg + residual + LN
  k_z256 <<<n, 256, 0, stream>>>(hw3h, b3, ptrc, csrc, dinv, resid, lng, lnb, zh);
  // 15-16: pool + final
  k_pool <<<64, 256, 0, stream>>>(zh, poolu, n);
  k_final<<<1, 64, 0, stream>>>(poolu, Wf, bfv, out);
}

// Round 6
// 298.225 us; speedup vs baseline: 1.5178x; 1.0903x over previous
//
#include <hip/hip_runtime.h>
#include <hip/hip_fp16.h>
#include <cstdint>
#include <cstddef>

#define NNODES 8192
#define NEDGES 262144

typedef _Float16 f16x8 __attribute__((ext_vector_type(8)));
typedef float    f32x4 __attribute__((ext_vector_type(4)));

__device__ __forceinline__ float leaky(float v){ return v > 0.f ? v : 0.01f*v; }

__device__ __forceinline__ unsigned fmap(float f){
  unsigned u = __float_as_uint(f);
  return (u & 0x80000000u) ? ~u : (u | 0x80000000u);
}
__device__ __forceinline__ float funmap(unsigned u){
  return (u & 0x80000000u) ? __uint_as_float(u & 0x7FFFFFFFu) : __uint_as_float(~u);
}

// ================= k_pre: conversions / transposes / zeroing / small vectors =======
__global__ __launch_bounds__(256) void k_pre(
    const float* __restrict__ x, const float* __restrict__ Wq, const float* __restrict__ Wk,
    const float* __restrict__ Wr, const float* __restrict__ W1, const float* __restrict__ W2,
    const float* __restrict__ W3, const float* __restrict__ bq, const float* __restrict__ bk,
    __half* xh, __half* Wqh, __half* Wkh, __half* Wrt, __half* W1t, __half* W2t, __half* W3t,
    float* bqk, float* wb, float* s0p,
    int* degc, int* degr, float* sw3, unsigned* poolu){
  int b = blockIdx.x, t = threadIdx.x;
  if (b < 4096){
    int idx = b*256 + t;
    xh[idx] = __float2half(x[idx]);
  } else if (b < 4352){
    int idx = (b-4096)*256 + t;
    Wqh[idx] = __float2half(Wq[idx]);
  } else if (b < 4608){
    int idx = (b-4352)*256 + t;
    Wkh[idx] = __float2half(Wk[idx]);
  } else if (b < 4640){         // Wr[128][64] -> Wrt[64][128]
    int idx = (b-4608)*256 + t;
    int nn = idx >> 7, k = idx & 127;
    Wrt[idx] = __float2half(Wr[k*64 + nn]);
  } else if (b < 4704){         // W1[128][128] -> W1t[128][128]
    int idx = (b-4640)*256 + t;
    int nn = idx >> 7, k = idx & 127;
    W1t[idx] = __float2half(W1[k*128 + nn]);
  } else if (b < 4832){         // W2[128][256] -> W2t[256][128]
    int idx = (b-4704)*256 + t;
    int nn = idx >> 7, k = idx & 127;
    W2t[idx] = __float2half(W2[k*256 + nn]);
  } else if (b < 4896){         // W3[256][64] -> W3t[64][256]
    int idx = (b-4832)*256 + t;
    int nn = idx >> 8, k = idx & 255;
    W3t[idx] = __float2half(W3[k*64 + nn]);
  } else if (b == 4896){
    int c = t;
    float a=0.f, bb=0.f;
    for (int o=0;o<256;++o){
      a  = fmaf(Wk[c*256+o], bq[o], a);
      bb = fmaf(Wq[c*256+o], bk[o], bb);
    }
    bqk[c]=a; wb[c]=bb;
    __shared__ float red[256];
    red[c] = bq[c]*bk[c];
    __syncthreads();
    for (int off=128; off; off>>=1){ if (c<off) red[c]+=red[c+off]; __syncthreads(); }
    if (c==0) s0p[0]=red[0];
  } else if (b < 4961){
    int idx = (b-4897)*256 + t;
    if (idx < 8192) degc[idx]=0; else degr[idx-8192]=0;
  } else {
    if (t < 64){ sw3[t]=0.f; poolu[t]=0u; }
  }
}

// ---------------- degrees ----------------
__global__ void k_degree(const int* __restrict__ ei, int* degc, int* degr, int E){
  int e = blockIdx.x*blockDim.x + threadIdx.x;
  if (e >= E) return;
  atomicAdd(&degc[ei[E+e]], 1);
  atomicAdd(&degr[ei[e]],   1);
}

// -------- shuffle-based exclusive scan + prep (block 0: col side w/ dinv; block 1: row side)
__global__ __launch_bounds__(1024) void k_scan(const int* __restrict__ degc,
    const int* __restrict__ degr, int* __restrict__ ptrc, int* __restrict__ ptrr,
    int* __restrict__ curc, int* __restrict__ curr, float* __restrict__ dinv, int n){
  const int* deg = blockIdx.x ? degr : degc;
  int* ptr = blockIdx.x ? ptrr : ptrc;
  int* cur = blockIdx.x ? curr : curc;
  int t = threadIdx.x, lane = t & 63, wid = t >> 6;   // 16 waves
  int base = t*8;
  int dv[8], loc[8]; int s = 0;
  #pragma unroll
  for (int q=0;q<8;q++){ dv[q]=deg[base+q]; loc[q]=s; s += dv[q]; }
  // inclusive wave scan of s
  int sc = s;
  #pragma unroll
  for (int o=1;o<64;o<<=1){ int v = __shfl_up(sc, o, 64); if (lane >= o) sc += v; }
  __shared__ int wsum[16];
  if (lane==63) wsum[wid] = sc;
  __syncthreads();
  if (wid==0){
    int v = (lane<16) ? wsum[lane] : 0;
    #pragma unroll
    for (int o=1;o<16;o<<=1){ int u = __shfl_up(v, o, 64); if (lane >= o) v += u; }
    if (lane<16) wsum[lane] = v;
  }
  __syncthreads();
  int prev = sc - s + (wid ? wsum[wid-1] : 0);
  #pragma unroll
  for (int q=0;q<8;q++){
    int p = prev + loc[q];
    ptr[base+q] = p;
    cur[base+q] = p;
    if (!blockIdx.x) dinv[base+q] = rsqrtf((float)(dv[q]+1));
  }
  if (t==1023) ptr[n] = prev + s;
}

// ---------------- MFMA GEMM tile (device): C64x64 = A[.,K] @ Bt[.,K]^T ----------------
// frag layouts (m91/m120-verified): A[m=lane&15][k=quad*8+j]; C/D row=quad*4+reg, col=lane&15
__device__ __forceinline__ void gemm_tile(const __half* __restrict__ A,
    const __half* __restrict__ Bt, const float* __restrict__ bias,
    float* __restrict__ Cf, __half* __restrict__ Ch, float* __restrict__ csum,
    int K, int N, int act, int bx, int by,
    _Float16 (*As)[40], _Float16 (*Bs)[40], float* cs){
  int t = threadIdx.x, w = t>>6, lane = t&63;
  int m0 = bx*64, n0 = by*64;
  int quad = lane>>4, l15 = lane&15;
  int srow = t>>2, soff = (t&3)*8;
  f32x4 acc0 = {0.f,0.f,0.f,0.f}, acc1 = acc0, acc2 = acc0, acc3 = acc0;
  for (int k0 = 0; k0 < K; k0 += 32){
    *(uint4*)&As[srow][soff] = *(const uint4*)(A  + (size_t)(m0+srow)*K + k0 + soff);
    *(uint4*)&Bs[srow][soff] = *(const uint4*)(Bt + (size_t)(n0+srow)*K + k0 + soff);
    __syncthreads();
    f16x8 af = *(const f16x8*)&As[w*16 + l15][quad*8];
    f16x8 b0 = *(const f16x8*)&Bs[ 0 + l15][quad*8];
    f16x8 b1 = *(const f16x8*)&Bs[16 + l15][quad*8];
    f16x8 b2 = *(const f16x8*)&Bs[32 + l15][quad*8];
    f16x8 b3 = *(const f16x8*)&Bs[48 + l15][quad*8];
    acc0 = __builtin_amdgcn_mfma_f32_16x16x32_f16(af, b0, acc0, 0,0,0);
    acc1 = __builtin_amdgcn_mfma_f32_16x16x32_f16(af, b1, acc1, 0,0,0);
    acc2 = __builtin_amdgcn_mfma_f32_16x16x32_f16(af, b2, acc2, 0,0,0);
    acc3 = __builtin_amdgcn_mfma_f32_16x16x32_f16(af, b3, acc3, 0,0,0);
    __syncthreads();
  }
  f32x4 accs[4] = {acc0, acc1, acc2, acc3};
  if (csum){
    if (t < 64) cs[t] = 0.f;
    __syncthreads();
    #pragma unroll
    for (int nt=0; nt<4; ++nt){
      float p = accs[nt][0]+accs[nt][1]+accs[nt][2]+accs[nt][3];
      atomicAdd(&cs[nt*16 + l15], p);
    }
    __syncthreads();
    if (t < 64) atomicAdd(&csum[n0 + t], cs[t]);
  }
  #pragma unroll
  for (int nt=0; nt<4; ++nt){
    int col = n0 + nt*16 + l15;
    float bv = bias ? bias[col] : 0.f;
    #pragma unroll
    for (int r=0;r<4;r++){
      int row = m0 + w*16 + quad*4 + r;
      float v = accs[nt][r] + bv;
      if (act) v = leaky(v);
      if (Cf) Cf[(size_t)row*N + col] = v;
      if (Ch) Ch[(size_t)row*N + col] = __float2half(v);
    }
  }
}

// ---------------- standalone GEMM wrapper (2D grid) ----------------
__global__ __launch_bounds__(256) void k_gemm(const __half* __restrict__ A,
    const __half* __restrict__ Bt, const float* __restrict__ bias,
    float* __restrict__ Cf, __half* __restrict__ Ch, float* __restrict__ csum,
    int K, int N, int act){
  __shared__ _Float16 As[64][40];
  __shared__ _Float16 Bs[64][40];
  __shared__ float cs[64];
  gemm_tile(A, Bt, bias, Cf, Ch, csum, K, N, act, blockIdx.x, blockIdx.y, As, Bs, cs);
}

// ---------------- mix1: CSR scatter + Wqkt gemm + resid gemm ----------------
__global__ __launch_bounds__(256) void k_mix1(const int* __restrict__ ei,
    int* curc, int* curr, int* csrc, int* csrd, int E,
    const __half* Wkh, const __half* Wqh, __half* Wqkt,
    const __half* xh, const __half* Wrt, const float* br, float* resid){
  __shared__ _Float16 As[64][40];
  __shared__ _Float16 Bs[64][40];
  int b = blockIdx.x;
  int SB = E/256;                       // 1024 scatter blocks
  if (b < SB){
    int e = b*256 + threadIdx.x;
    int r = ei[e], c = ei[E+e];
    int p1 = atomicAdd(&curc[c],1); csrc[p1] = r;   // GCN: in-neighbors of col c
    int p2 = atomicAdd(&curr[r],1); csrd[p2] = c;   // attention: neighbors of row r
  } else if (b < SB+16){
    int bb = b - SB;                    // Wqkt[n][k] = (Wq@Wk^T)^T = Wk@Wq^T
    gemm_tile(Wkh, Wqh, nullptr, nullptr, Wqkt, nullptr, 256, 256, 0, bb&3, bb>>2, As, Bs, nullptr);
  } else {
    gemm_tile(xh, Wrt, br, resid, nullptr, nullptr, 128, 64, 0, b-(SB+16), 0, As, Bs, nullptr);
  }
}

// ---------------- mix2: G = h2@W3 (+colsum) and qt = h2@Wqk + bqk ----------------
__global__ __launch_bounds__(256) void k_mix2(const __half* h2h, const __half* W3t,
    __half* gh, float* sw3, const __half* Wqkt, const float* bqk, __half* qth){
  __shared__ _Float16 As[64][40];
  __shared__ _Float16 Bs[64][40];
  __shared__ float cs[64];
  int b = blockIdx.x;
  if (b < 128){
    gemm_tile(h2h, W3t, nullptr, nullptr, gh, sw3, 256, 64, 0, b, 0, As, Bs, cs);
  } else {
    int bb = b - 128;
    gemm_tile(h2h, Wqkt, bqk, nullptr, qth, nullptr, 256, 256, 0, bb>>2, bb&3, As, Bs, cs);
  }
}

// ---------------- GCN aggregation, F=128, fp16 in/out: 4 waves split edges --------------
__global__ __launch_bounds__(256) void k_agg128(const __half* __restrict__ in,
    const int* __restrict__ ptr, const int* __restrict__ src,
    const float* __restrict__ dinv, __half* __restrict__ outp){
  int c = blockIdx.x, t = threadIdx.x, w = t>>6, lane = t&63;
  float dc = dinv[c];
  float2 acc = make_float2(0.f, 0.f);
  int e0 = ptr[c], e1 = ptr[c+1];
  for (int e = e0 + w; e < e1; e += 4){
    int r = src[e];
    float2 hv = __half22float2(*(const __half2*)(in + (size_t)r*128 + lane*2));
    float sc = dinv[r];
    acc.x = fmaf(sc, hv.x, acc.x);
    acc.y = fmaf(sc, hv.y, acc.y);
  }
  __shared__ float2 red[4][64];
  red[w][lane] = acc;
  __syncthreads();
  if (w == 0){
    float2 s = red[0][lane];
    float2 b1 = red[1][lane], b2 = red[2][lane], b3 = red[3][lane];
    s.x += b1.x + b2.x + b3.x;
    s.y += b1.y + b2.y + b3.y;
    float2 self = __half22float2(*(const __half2*)(in + (size_t)c*128 + lane*2));
    *(__half2*)(outp + (size_t)c*128 + lane*2) =
        __floats2half2_rn(dc*(dc*self.x + s.x), dc*(dc*self.y + s.y));
  }
}

// ---------------- fused attention (projected 64-dim), 2 waves/node, 4-edge ILP ----------
// s_ij = qt_i.h2_j + c_i ; c_i = h2_i.wb + s0 ; g = h2@W3 ; sw3 = colsum(g)
// hw3[i,f] = (sw3[f] + sum_nbr (exp(s_ij)-1) g_j[f]) / ((n-k_i) + sum exp(s_ij))
__global__ __launch_bounds__(256) void k_attn5(const __half* __restrict__ h2h,
    const __half* __restrict__ qth, const __half* __restrict__ gh,
    const float* __restrict__ sw3, const float* __restrict__ wb,
    const float* __restrict__ s0p, const int* __restrict__ ptrr,
    const int* __restrict__ csrd, __half* __restrict__ hw3h, int n){
  int t = threadIdx.x;
  int slot = t>>7;            // node within block (0,1)
  int w2 = (t>>6)&1;          // wave within node
  int lane = t&63;
  int i = blockIdx.x*2 + slot;
  int fo = lane*4;
  uint2 qtu = *(const uint2*)(qth + (size_t)i*256 + fo);
  float2 qa = __half22float2(*(__half2*)&qtu.x);
  float2 qb = __half22float2(*(__half2*)&qtu.y);
  float4 wbv = *(const float4*)(wb + fo);
  uint2 hiu  = *(const uint2*)(h2h + (size_t)i*256 + fo);
  float2 hia = __half22float2(*(__half2*)&hiu.x);
  float2 hib = __half22float2(*(__half2*)&hiu.y);
  float pv = hia.x*wbv.x + hia.y*wbv.y + hib.x*wbv.z + hib.y*wbv.w;
  #pragma unroll
  for (int mm=32; mm; mm>>=1) pv += __shfl_xor(pv, mm, 64);
  float Ei = __expf(pv + s0p[0]);
  int e0 = ptrr[i], e1 = ptrr[i+1];
  float acc = 0.f, dsum = 0.f;
  // wave w2 takes edges e0+w2, e0+w2+2, ... ; 4 concurrent edges per iteration
  for (int eb = e0 + w2; eb < e1; eb += 8){
    int j[4]; bool val[4];
    #pragma unroll
    for (int u=0;u<4;u++){
      int e = eb + 2*u;
      val[u] = (e < e1);
      j[u] = csrd[val[u] ? e : (e1-1)];
    }
    uint2 hv[4]; float gv[4];
    #pragma unroll
    for (int u=0;u<4;u++){
      hv[u] = *(const uint2*)(h2h + (size_t)j[u]*256 + fo);
      gv[u] = __half2float(gh[(size_t)j[u]*64 + lane]);
    }
    float d[4];
    #pragma unroll
    for (int u=0;u<4;u++){
      float2 ha = __half22float2(*(__half2*)&hv[u].x);
      float2 hb = __half22float2(*(__half2*)&hv[u].y);
      d[u] = qa.x*ha.x + qa.y*ha.y + qb.x*hb.x + qb.y*hb.y;
    }
    #pragma unroll
    for (int mm=32; mm; mm>>=1){
      #pragma unroll
      for (int u=0;u<4;u++) d[u] += __shfl_xor(d[u], mm, 64);
    }
    #pragma unroll
    for (int u=0;u<4;u++){
      if (val[u]){
        float we = Ei * __expf(d[u]);
        dsum += we;
        acc = fmaf(we - 1.f, gv[u], acc);
      }
    }
  }
  __shared__ float sacc[2][2][64];
  __shared__ float sds[2][2];
  sacc[slot][w2][lane] = acc;
  if (lane==0) sds[slot][w2] = dsum;
  __syncthreads();
  if (w2==0){
    float a2 = sacc[slot][0][lane] + sacc[slot][1][lane];
    float den = (float)(n - (e1 - e0)) + sds[slot][0] + sds[slot][1];
    hw3h[(size_t)i*64 + lane] = __float2half((sw3[lane] + a2) / den);
  }
}

// ---------------- fused conv3 agg + bias + leaky + residual + LayerNorm -> z fp16 -------
__global__ __launch_bounds__(256) void k_z256(const __half* __restrict__ hw3h,
    const float* __restrict__ b3, const int* __restrict__ ptrc,
    const int* __restrict__ csrc, const float* __restrict__ dinv,
    const float* __restrict__ resid, const float* __restrict__ lng,
    const float* __restrict__ lnb, __half* __restrict__ zh){
  int c = blockIdx.x, t = threadIdx.x, w = t>>6, lane = t&63;
  float dc = dinv[c];
  float acc = 0.f;
  int e0 = ptrc[c], e1 = ptrc[c+1];
  for (int e = e0 + w; e < e1; e += 4){
    int r = csrc[e];
    acc = fmaf(dinv[r], __half2float(hw3h[(size_t)r*64 + lane]), acc);
  }
  __shared__ float red[4][64];
  red[w][lane] = acc;
  __syncthreads();
  if (w == 0){
    acc = red[0][lane]+red[1][lane]+red[2][lane]+red[3][lane];
    float self = __half2float(hw3h[(size_t)c*64 + lane]);
    float v = leaky(dc*(dc*self + acc) + b3[lane]) + resid[(size_t)c*64 + lane];
    float s = v;
    #pragma unroll
    for (int mm=32; mm; mm>>=1) s += __shfl_xor(s, mm, 64);
    float mu = s * (1.0f/64.0f);
    float d = v - mu;
    float s2 = d*d;
    #pragma unroll
    for (int mm=32; mm; mm>>=1) s2 += __shfl_xor(s2, mm, 64);
    zh[(size_t)c*64 + lane] =
        __float2half(d * rsqrtf(s2*(1.0f/64.0f) + 1e-5f) * lng[lane] + lnb[lane]);
  }
}

// ---------------- max pool (fp16 in, monotonic uint atomicMax) ----------------
__global__ __launch_bounds__(256) void k_pool(const __half* __restrict__ zh,
    unsigned* __restrict__ poolu, int n){
  int f = threadIdx.x & 63, rg = threadIdx.x >> 6;
  float m = -3.402823466e38f;
  int r0 = blockIdx.x * 128;
  for (int r = r0 + rg; r < r0 + 128; r += 4)
    m = fmaxf(m, __half2float(zh[(size_t)r*64 + f]));
  __shared__ float sh[4][64];
  sh[rg][f] = m; __syncthreads();
  if (rg == 0){
    m = fmaxf(fmaxf(sh[0][f],sh[1][f]), fmaxf(sh[2][f],sh[3][f]));
    atomicMax(&poolu[f], fmap(m));
  }
}

// ---------------- final ----------------
__global__ __launch_bounds__(64) void k_final(const unsigned* __restrict__ poolu,
    const float* __restrict__ Wf, const float* __restrict__ bfv, float* __restrict__ out){
  __shared__ float p[64];
  int t = threadIdx.x;
  p[t] = funmap(poolu[t]);
  __syncthreads();
  if (t < 16){
    float acc = bfv[t];
    #pragma unroll
    for (int f=0; f<64; ++f) acc = fmaf(p[f], Wf[f*16 + t], acc);
    out[t] = acc;
  }
}

extern "C" void kernel_launch(void* const* d_in, const int* in_sizes, int n_in,
                              void* d_out, int out_size, void* d_ws, size_t ws_size,
                              hipStream_t stream){
  const float* x   = (const float*)d_in[0];
  const int*   ei  = (const int*)d_in[1];
  const float* W1  = (const float*)d_in[2];
  const float* b1  = (const float*)d_in[3];
  const float* W2  = (const float*)d_in[4];
  const float* b2  = (const float*)d_in[5];
  const float* W3  = (const float*)d_in[6];
  const float* b3  = (const float*)d_in[7];
  const float* Wk  = (const float*)d_in[8];
  const float* bk  = (const float*)d_in[9];
  const float* Wq  = (const float*)d_in[10];
  const float* bq  = (const float*)d_in[11];
  const float* Wr  = (const float*)d_in[12];
  const float* br  = (const float*)d_in[13];
  const float* lng = (const float*)d_in[14];
  const float* lnb = (const float*)d_in[15];
  const float* Wf  = (const float*)d_in[16];
  const float* bfv = (const float*)d_in[17];
  float* out = (float*)d_out;

  const int n = NNODES, E = NEDGES;
  char* ws = (char*)d_ws; size_t off = 0;
  auto alloc = [&](size_t bytes)->void*{
    void* p = ws + off; off += (bytes + 255) & ~(size_t)255; return p;
  };
  __half* xh   = (__half*)alloc((size_t)n*128*2);
  __half* xah  = (__half*)alloc((size_t)n*128*2);
  __half* h1h  = (__half*)alloc((size_t)n*128*2);
  __half* h1ah = (__half*)alloc((size_t)n*128*2);
  __half* h2h  = (__half*)alloc((size_t)n*256*2);
  __half* qth  = (__half*)alloc((size_t)n*256*2);
  __half* gh   = (__half*)alloc((size_t)n*64*2);
  __half* hw3h = (__half*)alloc((size_t)n*64*2);
  float*  resid= (float*)alloc((size_t)n*64*4);
  __half* zh   = (__half*)alloc((size_t)n*64*2);
  float*  dinv = (float*)alloc((size_t)n*4);
  float*  sw3  = (float*)alloc(64*4);
  __half* Wqh  = (__half*)alloc(256*256*2);
  __half* Wkh  = (__half*)alloc(256*256*2);
  __half* Wqkt = (__half*)alloc(256*256*2);
  __half* Wrt  = (__half*)alloc(128*64*2);
  __half* W1t  = (__half*)alloc(128*128*2);
  __half* W2t  = (__half*)alloc(128*256*2);
  __half* W3t  = (__half*)alloc(256*64*2);
  float*  bqk  = (float*)alloc(256*4);
  float*  wb   = (float*)alloc(256*4);
  float*  s0p  = (float*)alloc(4);
  int* degc = (int*)alloc((size_t)n*4);
  int* degr = (int*)alloc((size_t)n*4);
  int* ptrc = (int*)alloc((size_t)(n+1)*4);
  int* ptrr = (int*)alloc((size_t)(n+1)*4);
  int* curc = (int*)alloc((size_t)n*4);
  int* curr = (int*)alloc((size_t)n*4);
  int* csrc = (int*)alloc((size_t)E*4);
  int* csrd = (int*)alloc((size_t)E*4);
  unsigned* poolu = (unsigned*)alloc(64*4);

  // 1: all conversions, transposes, zeroing, small vectors
  k_pre<<<dim3(4962), 256, 0, stream>>>(x, Wq, Wk, Wr, W1, W2, W3, bq, bk,
      xh, Wqh, Wkh, Wrt, W1t, W2t, W3t, bqk, wb, s0p, degc, degr, sw3, poolu);
  // 2: degrees
  k_degree<<<dim3(E/256), 256, 0, stream>>>(ei, degc, degr, E);
  // 3: scans (+dinv, cursors)
  k_scan  <<<2, 1024, 0, stream>>>(degc, degr, ptrc, ptrr, curc, curr, dinv, n);
  // 4: CSR scatter + Wqkt gemm + resid gemm
  k_mix1  <<<dim3(E/256 + 16 + n/64), 256, 0, stream>>>(ei, curc, curr, csrc, csrd, E,
      Wkh, Wqh, Wqkt, xh, Wrt, br, resid);
  // 5-6: conv1 = leaky((A.x)@W1 + b1)
  k_agg128<<<n, 256, 0, stream>>>(xh, ptrc, csrc, dinv, xah);
  k_gemm  <<<dim3(n/64, 2), 256, 0, stream>>>(xah, W1t, b1, nullptr, h1h, nullptr, 128, 128, 1);
  // 7-8: conv2 = leaky((A.h1)@W2 + b2)
  k_agg128<<<n, 256, 0, stream>>>(h1h, ptrc, csrc, dinv, h1ah);
  k_gemm  <<<dim3(n/64, 4), 256, 0, stream>>>(h1ah, W2t, b2, nullptr, h2h, nullptr, 128, 256, 1);
  // 9: G = h2@W3 (+colsum) and qt = h2@Wqk + bqk
  k_mix2  <<<dim3(128 + 512), 256, 0, stream>>>(h2h, W3t, gh, sw3, Wqkt, bqk, qth);
  // 10: fused attention -> hw3h (projected 64-dim)
  k_attn5 <<<dim3(n/2), 256, 0, stream>>>(h2h, qth, gh, sw3, wb, s0p, ptrr, csrd, hw3h, n);
  // 11: conv3 agg + residual + LN
  k_z256  <<<n, 256, 0, stream>>>(hw3h, b3, ptrc, csrc, dinv, resid, lng, lnb, zh);
  // 12-13: pool + final
  k_pool  <<<64, 256, 0, stream>>>(zh, poolu, n);
  k_final <<<1, 64, 0, stream>>>(poolu, Wf, bfv, out);
}